// Round 1
// 771.794 us; speedup vs baseline: 1.1673x; 1.1673x over previous
//
#include <hip/hip_runtime.h>
#include <hip/hip_bf16.h>
#include <cstdint>
#include <cstddef>

#define DIM 192
#define NSL 11
#define NB 64
#define NN 4096
#define HIDN 128
#define NCHP 16        // chunks per batch in k_iter (256 rows each)
#define TROWS 32       // rows per LDS tile in k_iter (8 tiles per chunk)
#define NT 8
#define LN_EPS 1e-5f
#define EPS_A 1e-8f
#define SCALE_Q 0.07216878364870323f  // 192^-0.5

// ---------------------------------------------------------------- utilities
__device__ __forceinline__ float wred(float v) {
#pragma unroll
  for (int m = 32; m; m >>= 1) v += __shfl_xor(v, m, 64);
  return v;
}

// async global->LDS, 16B per lane. LDS dest is wave-uniform base + lane*16 (HW).
typedef const __attribute__((address_space(1))) void gas_void;
typedef __attribute__((address_space(3))) void las_void;
__device__ __forceinline__ void gload_lds16(const void* g, void* l) {
  __builtin_amdgcn_global_load_lds((gas_void*)g, (las_void*)l, 16, 0, 0);
}

// ---------------------------------------------------------------- one-time weight transpose (64x64 LDS tiles)
__global__ __launch_bounds__(256) void k_tr(
    const float* __restrict__ Wih, const float* __restrict__ Whh, const float* __restrict__ Wk,
    float* __restrict__ WihT, float* __restrict__ WhhT, float* __restrict__ WkT) {
  __shared__ float t[64][65];
  int tile = blockIdx.x;
  const float* src; float* dst; int R, C;
  if (tile < 27)      { src = Wih; dst = WihT; R = 576; C = 192; }
  else if (tile < 54) { src = Whh; dst = WhhT; R = 576; C = 192; tile -= 27; }
  else                { src = Wk;  dst = WkT;  R = 192; C = 192; tile -= 54; }
  const int ntc = C >> 6;
  const int tr = tile / ntc, tc = tile % ntc;
  const int lane = threadIdx.x & 63, w = threadIdx.x >> 6;
#pragma unroll
  for (int i = 0; i < 16; ++i) {
    int row = w * 16 + i;
    t[row][lane] = src[(size_t)(tr * 64 + row) * C + tc * 64 + lane];
  }
  __syncthreads();
#pragma unroll
  for (int i = 0; i < 16; ++i) {
    int row = w * 16 + i;
    dst[(size_t)(tc * 64 + row) * R + tr * 64 + lane] = t[lane][row];
  }
}

// ---------------------------------------------------------------- k_prep: grid (64,4), 3 slots/block
__global__ __launch_bounds__(192) void k_prep(
    const float* __restrict__ lnw, const float* __restrict__ lnb,
    const float* __restrict__ Wq, const float* __restrict__ bq,
    const float* __restrict__ WkT, const float* __restrict__ bk,
    const float* __restrict__ xw, const float* __restrict__ xb,
    const float* __restrict__ noise, const float* __restrict__ mu0, const float* __restrict__ sig,
    float* __restrict__ slots_ws,
    float* __restrict__ qt, float* __restrict__ t0g, float* __restrict__ cpg) {
  const int b = blockIdx.x, kg = blockIdx.y, tid = threadIdx.x;
  const int k0 = kg * 3, kcnt = (kg == 3) ? 2 : 3;
  const int wave = tid >> 6, lane = tid & 63;
  const int j = tid;
  __shared__ __align__(16) float sn[3][DIM];
  __shared__ __align__(16) float qb[3][DIM];
  __shared__ float red[3][3][2];

#pragma unroll
  for (int kk = 0; kk < 3; ++kk) {
    if (kk < kcnt) {
      float v = mu0[j] + sig[j] * noise[(size_t)(b * NSL + k0 + kk) * DIM + j];
      sn[kk][j] = v;
      slots_ws[(size_t)(b * NSL + k0 + kk) * DIM + j] = v;
    } else sn[kk][j] = 0.f;
  }
  __syncthreads();

  for (int kk = wave; kk < 3; kk += 3) {
    float a = sn[kk][lane], c = sn[kk][lane + 64], e = sn[kk][lane + 128];
    float s = wred(a + c + e), ss = wred(a * a + c * c + e * e);
    float mu = s * (1.0f / DIM), var = ss * (1.0f / DIM) - mu * mu;
    float rstd = rsqrtf(var + LN_EPS);
    sn[kk][lane]       = (a - mu) * rstd * lnw[lane]       + lnb[lane];
    sn[kk][lane + 64]  = (c - mu) * rstd * lnw[lane + 64]  + lnb[lane + 64];
    sn[kk][lane + 128] = (e - mu) * rstd * lnw[lane + 128] + lnb[lane + 128];
  }
  __syncthreads();

  float acc[3];
  const float bj = bq[j];
#pragma unroll
  for (int kk = 0; kk < 3; ++kk) acc[kk] = bj;
  for (int d = 0; d < DIM; d += 4) {
    float w0 = Wq[(d + 0) * DIM + j], w1 = Wq[(d + 1) * DIM + j];
    float w2 = Wq[(d + 2) * DIM + j], w3 = Wq[(d + 3) * DIM + j];
#pragma unroll
    for (int kk = 0; kk < 3; ++kk) {
      float4 s4 = *(const float4*)&sn[kk][d];
      acc[kk] = fmaf(s4.w, w3, fmaf(s4.z, w2, fmaf(s4.y, w1, fmaf(s4.x, w0, acc[kk]))));
    }
  }
#pragma unroll
  for (int kk = 0; kk < 3; ++kk) qb[kk][j] = acc[kk];
  __syncthreads();

  float qk[3];
#pragma unroll
  for (int kk = 0; kk < 3; ++kk) qk[kk] = 0.f;
  for (int d = 0; d < DIM; d += 4) {
    float w0 = WkT[(d + 0) * DIM + j], w1 = WkT[(d + 1) * DIM + j];
    float w2 = WkT[(d + 2) * DIM + j], w3 = WkT[(d + 3) * DIM + j];
#pragma unroll
    for (int kk = 0; kk < 3; ++kk) {
      float4 q4 = *(const float4*)&qb[kk][d];
      qk[kk] = fmaf(q4.w, w3, fmaf(q4.z, w2, fmaf(q4.y, w1, fmaf(q4.x, w0, qk[kk]))));
    }
  }
  const float wj = xw[j], bxj = xb[j], bkj = bk[j];
#pragma unroll
  for (int kk = 0; kk < 3; ++kk) {
    float qtv = SCALE_Q * wj * qk[kk];
    if (kk < kcnt) qt[(size_t)(b * NSL + k0 + kk) * DIM + j] = qtv;
    float r1 = wred(qtv);
    float r2 = wred(SCALE_Q * (bxj * qk[kk] + qb[kk][j] * bkj));
    if (lane == 0) { red[wave][kk][0] = r1; red[wave][kk][1] = r2; }
  }
  __syncthreads();
  if (tid < kcnt) {
    t0g[b * NSL + k0 + tid] = red[0][tid][0] + red[1][tid][0] + red[2][tid][0];
    cpg[b * NSL + k0 + tid] = red[0][tid][1] + red[1][tid][1] + red[2][tid][1];
  }
}

// ---------------------------------------------------------------- fused iteration kernel
// R9 restructure: the R8 kernel spilled the float4 xv[12] prefetch to scratch
// (WRITE_SIZE 214 MB vs 20 MB true writes; ~186 spilled floats/thread matches
// xv written 4x). Fix is structural: 32-row double-buffered LDS tiles staged by
// global_load_lds (zero staging VGPRs/VALU), and 2 rows per 16-lane group so
// dot[] halves to [2][11]. Peak live regs ~110 < 128 -> no scratch.
// Linear [32][192] tile + consecutive-16-lane groups is bank-conflict-free
// (8 consecutive lanes share a row, widx%8 distinct), so no XOR swizzle needed.
__global__ __launch_bounds__(256) void k_iter(
    const float* __restrict__ x, const float* __restrict__ qt,
    const float* __restrict__ t0g, const float* __restrict__ cpg,
    float* __restrict__ attn_out, float* __restrict__ P1p,
    float* __restrict__ S_p, float* __restrict__ m1_p) {
  __shared__ __align__(16) float xs[2][TROWS * DIM];   // 2 x 24576 B
  __shared__ __align__(16) float qs[NSL * DIM];        // 8448 B
  __shared__ __align__(16) float a_lds[TROWS][12];     // 1536 B
  __shared__ float rs_lds[TROWS];
  __shared__ float t0s[NSL], cps[NSL];
  __shared__ float redS[4][NSL], redM[4][NSL];

  const int b = blockIdx.x, ch = blockIdx.y, tid = threadIdx.x;
  const int lane = tid & 63, wv = tid >> 6;
  const int widx = tid & 15, g = tid >> 4;

  const float* xbase = x + ((size_t)b * NN + ch * 256) * DIM;

  // issue tile-0 DMA first so it overlaps the q/t0/cp staging below
  {
#pragma unroll
    for (int i = 0; i < 6; ++i) {
      int c = i * 4 + wv;                               // 24 x 1024B chunks
      gload_lds16(xbase + c * 256 + lane * 4, &xs[0][c * 256]);
    }
  }
  {
    const float4* src = (const float4*)(qt + (size_t)b * NSL * DIM);   // 528 float4
    float4* dst = (float4*)qs;
    dst[tid] = src[tid];
    dst[256 + tid] = src[256 + tid];
    if (tid < 16) dst[512 + tid] = src[512 + tid];
  }
  if (tid < NSL) { t0s[tid] = t0g[b * NSL + tid]; cps[tid] = cpg[b * NSL + tid]; }

  float acc[3][NSL], sS[NSL], sM[NSL];
#pragma unroll
  for (int k = 0; k < NSL; ++k) {
    acc[0][k] = 0.f; acc[1][k] = 0.f; acc[2][k] = 0.f;
    sS[k] = 0.f; sM[k] = 0.f;
  }

#pragma unroll 1
  for (int T = 0; T < NT; ++T) {
    const int cur = T & 1;
    // A: full barrier (compiler drains vmcnt here -> prev prefetch has had a
    // whole tile of compute to land; also publishes qs/a_lds writes).
    __syncthreads();
    if (T < NT - 1) {
      // prefetch tile T+1 into the other buffer; stays in flight across this
      // tile's compute (barriers B/C below are raw, no drain).
      const float* src = xbase + (size_t)(T + 1) * TROWS * DIM;
      float* dstb = &xs[cur ^ 1][0];
#pragma unroll
      for (int i = 0; i < 6; ++i) {
        int c = i * 4 + wv;
        gload_lds16(src + c * 256 + lane * 4, dstb + c * 256);
      }
      asm volatile("s_waitcnt vmcnt(6)" ::: "memory");  // own cur-tile DMA done
    } else {
      asm volatile("s_waitcnt vmcnt(0)" ::: "memory");
    }
    __builtin_amdgcn_s_barrier();                       // B: xs[cur] staged by all waves
    const float* xc = &xs[cur][0];

    // ---- dots + LN stats: 16-lane group g owns rows {2g, 2g+1}
    float dot[2][NSL], st_s[2], st_ss[2];
#pragma unroll
    for (int rr = 0; rr < 2; ++rr) {
      st_s[rr] = 0.f; st_ss[rr] = 0.f;
#pragma unroll
      for (int k = 0; k < NSL; ++k) dot[rr][k] = 0.f;
    }
#pragma unroll
    for (int w = 0; w < 3; ++w) {
      const int c4 = widx + 16 * w;
      float4 xr[2];
#pragma unroll
      for (int rr = 0; rr < 2; ++rr) {
        xr[rr] = ((const float4*)xc)[(2 * g + rr) * 48 + c4];
        st_s[rr] += (xr[rr].x + xr[rr].y) + (xr[rr].z + xr[rr].w);
        st_ss[rr] = fmaf(xr[rr].x, xr[rr].x, fmaf(xr[rr].y, xr[rr].y,
                    fmaf(xr[rr].z, xr[rr].z, fmaf(xr[rr].w, xr[rr].w, st_ss[rr]))));
      }
#pragma unroll
      for (int k = 0; k < NSL; ++k) {
        float4 qv = *(const float4*)&qs[k * DIM + 4 * c4];
#pragma unroll
        for (int rr = 0; rr < 2; ++rr)
          dot[rr][k] = fmaf(xr[rr].w, qv.w, fmaf(xr[rr].z, qv.z,
                       fmaf(xr[rr].y, qv.y, fmaf(xr[rr].x, qv.x, dot[rr][k]))));
      }
    }
#pragma unroll
    for (int m = 1; m <= 8; m <<= 1) {
#pragma unroll
      for (int rr = 0; rr < 2; ++rr) {
        st_s[rr] += __shfl_xor(st_s[rr], m, 64);
        st_ss[rr] += __shfl_xor(st_ss[rr], m, 64);
#pragma unroll
        for (int k = 0; k < NSL; ++k) dot[rr][k] += __shfl_xor(dot[rr][k], m, 64);
      }
    }
    // ---- softmax: widx==0 handles row 2g, widx==8 handles row 2g+1.
    // Select into dsel with static indices (runtime-indexed reg arrays -> scratch).
    if ((widx & 7) == 0) {
      const int hi = widx >> 3;
      const int r = 2 * g + hi;
      float dsel[NSL];
#pragma unroll
      for (int k = 0; k < NSL; ++k) dsel[k] = (widx == 0) ? dot[0][k] : dot[1][k];
      float sts  = (widx == 0) ? st_s[0]  : st_s[1];
      float stss = (widx == 0) ? st_ss[0] : st_ss[1];
      float mu = sts * (1.0f / DIM);
      float var = stss * (1.0f / DIM) - mu * mu;
      float rstd = rsqrtf(var + LN_EPS);
      float murstd = mu * rstd;
      float dv[NSL];
#pragma unroll
      for (int k = 0; k < NSL; ++k) dv[k] = fmaf(rstd, dsel[k], fmaf(-murstd, t0s[k], cps[k]));
      float mx = dv[0];
#pragma unroll
      for (int k = 1; k < NSL; ++k) mx = fmaxf(mx, dv[k]);
      float es[NSL], sum = 0.f;
#pragma unroll
      for (int k = 0; k < NSL; ++k) { es[k] = __expf(dv[k] - mx); sum += es[k]; }
      float inv = 1.0f / sum;
#pragma unroll
      for (int k = 0; k < NSL; ++k) {
        float a = fmaf(es[k], inv, EPS_A);
        a_lds[r][k] = a;
        sS[k] += a;
        sM[k] = fmaf(a, murstd, sM[k]);
      }
      rs_lds[r] = rstd;
    }
    asm volatile("s_waitcnt lgkmcnt(0)" ::: "memory");  // a_lds/rs_lds committed
    __builtin_amdgcn_s_barrier();                       // C: raw (keep prefetch alive)

    // ---- attn_out: 352 values, 32-float coalesced runs
    {
      int idx = tid;
      attn_out[((size_t)(b * NSL + (idx >> 5))) * NN + ch * 256 + T * TROWS + (idx & 31)]
          = a_lds[idx & 31][idx >> 5];
      idx = tid + 256;
      if (idx < NSL * TROWS)
        attn_out[((size_t)(b * NSL + (idx >> 5))) * NN + ch * 256 + T * TROWS + (idx & 31)]
            = a_lds[idx & 31][idx >> 5];
    }
    // ---- PV accumulate: wave wv owns rows 4i+wv
#pragma unroll 4
    for (int i = 0; i < 8; ++i) {
      const int r = 4 * i + wv;
      float rst = rs_lds[r];
      float4 a0 = *(const float4*)&a_lds[r][0];
      float4 a1 = *(const float4*)&a_lds[r][4];
      float4 a2 = *(const float4*)&a_lds[r][8];
#pragma unroll
      for (int j = 0; j < 3; ++j) {
        const int col = lane + 64 * j;
        float t1 = rst * xc[r * DIM + col];
        acc[j][0]  = fmaf(a0.x, t1, acc[j][0]);
        acc[j][1]  = fmaf(a0.y, t1, acc[j][1]);
        acc[j][2]  = fmaf(a0.z, t1, acc[j][2]);
        acc[j][3]  = fmaf(a0.w, t1, acc[j][3]);
        acc[j][4]  = fmaf(a1.x, t1, acc[j][4]);
        acc[j][5]  = fmaf(a1.y, t1, acc[j][5]);
        acc[j][6]  = fmaf(a1.z, t1, acc[j][6]);
        acc[j][7]  = fmaf(a1.w, t1, acc[j][7]);
        acc[j][8]  = fmaf(a2.x, t1, acc[j][8]);
        acc[j][9]  = fmaf(a2.y, t1, acc[j][9]);
        acc[j][10] = fmaf(a2.z, t1, acc[j][10]);
      }
    }
  }

  __syncthreads();
  float* accbuf = &xs[0][0];                 // reuse tile buffers (12288 floats)
#pragma unroll
  for (int j = 0; j < 3; ++j)
#pragma unroll
    for (int k = 0; k < NSL; ++k)
      accbuf[tid * 33 + j * 11 + k] = acc[j][k];
  __syncthreads();
  if (tid < DIM) {
    const int l = tid & 63, j = tid >> 6;
#pragma unroll
    for (int k = 0; k < NSL; ++k) {
      float v = accbuf[(l) * 33 + j * 11 + k] + accbuf[(64 + l) * 33 + j * 11 + k]
              + accbuf[(128 + l) * 33 + j * 11 + k] + accbuf[(192 + l) * 33 + j * 11 + k];
      P1p[(((size_t)b * NCHP + ch) * NSL + k) * DIM + tid] = v;
    }
  }
#pragma unroll
  for (int k = 0; k < NSL; ++k) { sS[k] = wred(sS[k]); sM[k] = wred(sM[k]); }
  if (lane == 0) {
#pragma unroll
    for (int k = 0; k < NSL; ++k) { redS[wv][k] = sS[k]; redM[wv][k] = sM[k]; }
  }
  __syncthreads();
  if (tid < NSL) {
    S_p[((size_t)b * NCHP + ch) * NSL + tid]  = redS[0][tid] + redS[1][tid] + redS[2][tid] + redS[3][tid];
    m1_p[((size_t)b * NCHP + ch) * NSL + tid] = redM[0][tid] + redM[1][tid] + redM[2][tid] + redM[3][tid];
  }
}

// ---------------------------------------------------------------- k_step: grid (64,4), 3 slots/block, coalesced weights
__global__ __launch_bounds__(192) void k_step(
    const float* __restrict__ P1p, const float* __restrict__ m1_p, const float* __restrict__ S_p,
    const float* __restrict__ xw, const float* __restrict__ xb,
    const float* __restrict__ Wv, const float* __restrict__ bv,
    const float* __restrict__ slots_in,
    const float* __restrict__ WihT, const float* __restrict__ WhhT,
    const float* __restrict__ bih, const float* __restrict__ bhh,
    const float* __restrict__ mw, const float* __restrict__ mb,
    const float* __restrict__ W1, const float* __restrict__ b1,
    const float* __restrict__ W2, const float* __restrict__ b2,
    const float* __restrict__ sw, const float* __restrict__ sb,
    const float* __restrict__ Wq, const float* __restrict__ bq,
    const float* __restrict__ WkT, const float* __restrict__ bk,
    float* __restrict__ slots_ws, float* __restrict__ slots_out,
    float* __restrict__ qt, float* __restrict__ t0g, float* __restrict__ cpg) {
  const int b = blockIdx.x, kg = blockIdx.y, tid = threadIdx.x;
  const int k0 = kg * 3, kcnt = (kg == 3) ? 2 : 3;
  const int wave = tid >> 6, lane = tid & 63;
  const int j = tid;
  __shared__ __align__(16) float u[3][DIM];
  __shared__ __align__(16) float hp[3][DIM];
  __shared__ __align__(16) float h[3][DIM];
  __shared__ __align__(16) float hid[3][HIDN];
  __shared__ float red[3][3][2];

  const float wj = xw[j], bj = xb[j];
#pragma unroll
  for (int kk = 0; kk < 3; ++kk) {
    if (kk < kcnt) {
      float p = 0.f, S = 0.f, M = 0.f;
#pragma unroll
      for (int ch = 0; ch < NCHP; ++ch) {
        p += P1p[(((size_t)b * NCHP + ch) * NSL + k0 + kk) * DIM + j];
        S += S_p[((size_t)b * NCHP + ch) * NSL + k0 + kk];
        M += m1_p[((size_t)b * NCHP + ch) * NSL + k0 + kk];
      }
      float inv = 1.0f / S;
      u[kk][j]  = wj * (p - M) * inv + bj;
      hp[kk][j] = slots_in[(size_t)(b * NSL + k0 + kk) * DIM + j];
    } else { u[kk][j] = 0.f; hp[kk][j] = 0.f; }
  }
  __syncthreads();

  float upd[3];
  const float bvj = bv[j];
#pragma unroll
  for (int kk = 0; kk < 3; ++kk) upd[kk] = bvj;
  for (int d = 0; d < DIM; d += 4) {
    float w0 = Wv[(d + 0) * DIM + j], w1 = Wv[(d + 1) * DIM + j];
    float w2 = Wv[(d + 2) * DIM + j], w3 = Wv[(d + 3) * DIM + j];
#pragma unroll
    for (int kk = 0; kk < 3; ++kk) {
      float4 x4 = *(const float4*)&u[kk][d];
      upd[kk] = fmaf(x4.w, w3, fmaf(x4.z, w2, fmaf(x4.y, w1, fmaf(x4.x, w0, upd[kk]))));
    }
  }
  __syncthreads();
#pragma unroll
  for (int kk = 0; kk < 3; ++kk) u[kk][j] = upd[kk];
  __syncthreads();

  float xr[3], xz[3], xn[3], hr[3], hz[3], hn[3];
  {
    float br_ = bih[j], bz_ = bih[DIM + j], bn_ = bih[2 * DIM + j];
    float cr_ = bhh[j], cz_ = bhh[DIM + j], cn_ = bhh[2 * DIM + j];
#pragma unroll
    for (int kk = 0; kk < 3; ++kk) { xr[kk] = br_; xz[kk] = bz_; xn[kk] = bn_; hr[kk] = cr_; hz[kk] = cz_; hn[kk] = cn_; }
  }
  for (int d = 0; d < DIM; d += 2) {
#pragma unroll
    for (int dd = 0; dd < 2; ++dd) {
      const float* ihrow = WihT + (size_t)(d + dd) * 576;
      const float* hhrow = WhhT + (size_t)(d + dd) * 576;
      float ar = ihrow[j], az = ihrow[192 + j], an = ihrow[384 + j];
      float br = hhrow[j], bz = hhrow[192 + j], bn = hhrow[384 + j];
#pragma unroll
      for (int kk = 0; kk < 3; ++kk) {
        float uv = u[kk][d + dd];
        float pv = hp[kk][d + dd];
        xr[kk] = fmaf(uv, ar, xr[kk]);
        xz[kk] = fmaf(uv, az, xz[kk]);
        xn[kk] = fmaf(uv, an, xn[kk]);
        hr[kk] = fmaf(pv, br, hr[kk]);
        hz[kk] = fmaf(pv, bz, hz[kk]);
        hn[kk] = fmaf(pv, bn, hn[kk]);
      }
    }
  }
#pragma unroll
  for (int kk = 0; kk < 3; ++kk) {
    float r = 1.f / (1.f + __expf(-(xr[kk] + hr[kk])));
    float z = 1.f / (1.f + __expf(-(xz[kk] + hz[kk])));
    float n = tanhf(xn[kk] + r * hn[kk]);
    h[kk][j] = (1.f - z) * n + z * hp[kk][j];
  }
  __syncthreads();

  for (int kk = wave; kk < 3; kk += 3) {
    float a = h[kk][lane], c = h[kk][lane + 64], e = h[kk][lane + 128];
    float s = wred(a + c + e), ss = wred(a * a + c * c + e * e);
    float mu = s * (1.0f / DIM), var = ss * (1.0f / DIM) - mu * mu;
    float rstd = rsqrtf(var + LN_EPS);
    u[kk][lane]       = (a - mu) * rstd * mw[lane]       + mb[lane];
    u[kk][lane + 64]  = (c - mu) * rstd * mw[lane + 64]  + mb[lane + 64];
    u[kk][lane + 128] = (e - mu) * rstd * mw[lane + 128] + mb[lane + 128];
  }
  __syncthreads();

  for (int t = tid; t < kcnt * HIDN; t += 192) {
    int kk = t >> 7, c = t & (HIDN - 1);
    float acc = b1[c];
    for (int d = 0; d < DIM; d += 4) {
      float4 m4 = *(const float4*)&u[kk][d];
      acc = fmaf(m4.x, W1[(d + 0) * HIDN + c],
            fmaf(m4.y, W1[(d + 1) * HIDN + c],
            fmaf(m4.z, W1[(d + 2) * HIDN + c],
            fmaf(m4.w, W1[(d + 3) * HIDN + c], acc))));
    }
    hid[kk][c] = fmaxf(acc, 0.f);
  }
  __syncthreads();

#pragma unroll 1
  for (int kk = 0; kk < kcnt; ++kk) {
    float acc = b2[j];
    for (int c = 0; c < HIDN; c += 4) {
      float4 h4 = *(const float4*)&hid[kk][c];
      acc = fmaf(h4.x, W2[(c + 0) * DIM + j],
            fmaf(h4.y, W2[(c + 1) * DIM + j],
            fmaf(h4.z, W2[(c + 2) * DIM + j],
            fmaf(h4.w, W2[(c + 3) * DIM + j], acc))));
    }
    float outv = h[kk][j] + acc;
    size_t gi = (size_t)(b * NSL + k0 + kk) * DIM + j;
    slots_ws[gi] = outv;
    slots_out[gi] = outv;
    hp[kk][j] = outv;
  }
  __syncthreads();

  for (int kk = wave; kk < 3; kk += 3) {
    float a = hp[kk][lane], c = hp[kk][lane + 64], e = hp[kk][lane + 128];
    float s = wred(a + c + e), ss = wred(a * a + c * c + e * e);
    float mu = s * (1.0f / DIM), var = ss * (1.0f / DIM) - mu * mu;
    float rstd = rsqrtf(var + LN_EPS);
    u[kk][lane]       = (a - mu) * rstd * sw[lane]       + sb[lane];
    u[kk][lane + 64]  = (c - mu) * rstd * sw[lane + 64]  + sb[lane + 64];
    u[kk][lane + 128] = (e - mu) * rstd * sw[lane + 128] + sb[lane + 128];
  }
  __syncthreads();

  float qacc[3];
  const float bqj = bq[j];
#pragma unroll
  for (int kk = 0; kk < 3; ++kk) qacc[kk] = bqj;
  for (int d = 0; d < DIM; d += 4) {
    float w0 = Wq[(d + 0) * DIM + j], w1 = Wq[(d + 1) * DIM + j];
    float w2 = Wq[(d + 2) * DIM + j], w3 = Wq[(d + 3) * DIM + j];
#pragma unroll
    for (int kk = 0; kk < 3; ++kk) {
      float4 s4 = *(const float4*)&u[kk][d];
      qacc[kk] = fmaf(s4.w, w3, fmaf(s4.z, w2, fmaf(s4.y, w1, fmaf(s4.x, w0, qacc[kk]))));
    }
  }
  __syncthreads();
#pragma unroll
  for (int kk = 0; kk < 3; ++kk) h[kk][j] = qacc[kk];
  __syncthreads();

  float qk[3];
#pragma unroll
  for (int kk = 0; kk < 3; ++kk) qk[kk] = 0.f;
  for (int d = 0; d < DIM; d += 4) {
    float w0 = WkT[(d + 0) * DIM + j], w1 = WkT[(d + 1) * DIM + j];
    float w2 = WkT[(d + 2) * DIM + j], w3 = WkT[(d + 3) * DIM + j];
#pragma unroll
    for (int kk = 0; kk < 3; ++kk) {
      float4 q4 = *(const float4*)&h[kk][d];
      qk[kk] = fmaf(q4.w, w3, fmaf(q4.z, w2, fmaf(q4.y, w1, fmaf(q4.x, w0, qk[kk]))));
    }
  }
  const float wxj = xw[j], bxj = xb[j], bkj = bk[j];
#pragma unroll
  for (int kk = 0; kk < 3; ++kk) {
    float qtv = SCALE_Q * wxj * qk[kk];
    if (kk < kcnt) qt[(size_t)(b * NSL + k0 + kk) * DIM + j] = qtv;
    float r1 = wred(qtv);
    float r2 = wred(SCALE_Q * (bxj * qk[kk] + h[kk][j] * bkj));
    if (lane == 0) { red[wave][kk][0] = r1; red[wave][kk][1] = r2; }
  }
  __syncthreads();
  if (tid < kcnt) {
    t0g[b * NSL + k0 + tid] = red[0][tid][0] + red[1][tid][0] + red[2][tid][0];
    cpg[b * NSL + k0 + tid] = red[0][tid][1] + red[1][tid][1] + red[2][tid][1];
  }
}

// ---------------------------------------------------------------- launch
extern "C" void kernel_launch(void* const* d_in, const int* in_sizes, int n_in,
                              void* d_out, int out_size, void* d_ws, size_t ws_size,
                              hipStream_t stream) {
  const float* inputs      = (const float*)d_in[0];
  const float* noise       = (const float*)d_in[1];
  const float* slots_mu    = (const float*)d_in[2];
  const float* slots_sigma = (const float*)d_in[3];
  const float* ln_in_w     = (const float*)d_in[4];
  const float* ln_in_b     = (const float*)d_in[5];
  const float* ln_slots_w  = (const float*)d_in[6];
  const float* ln_slots_b  = (const float*)d_in[7];
  const float* ln_mlp_w    = (const float*)d_in[8];
  const float* ln_mlp_b    = (const float*)d_in[9];
  const float* Wq  = (const float*)d_in[10];
  const float* bq  = (const float*)d_in[11];
  const float* Wk  = (const float*)d_in[12];
  const float* bk  = (const float*)d_in[13];
  const float* Wv  = (const float*)d_in[14];
  const float* bv  = (const float*)d_in[15];
  const float* Wih = (const float*)d_in[16];
  const float* Whh = (const float*)d_in[17];
  const float* bih = (const float*)d_in[18];
  const float* bhh = (const float*)d_in[19];
  const float* W1  = (const float*)d_in[20];
  const float* b1  = (const float*)d_in[21];
  const float* W2  = (const float*)d_in[22];
  const float* b2  = (const float*)d_in[23];

  float* out = (float*)d_out;
  float* slots_out = out;                      // [64,11,192] fp32
  float* attn_out  = out + NB * NSL * DIM;     // [64,11,4096] fp32

  char* w = (char*)d_ws;
  float* slots = (float*)w;                    //  540672 B
  float* qt    = (float*)(w + 540672);         //  540672 B
  float* t0g   = (float*)(w + 1081344);        //    2816 B
  float* cpg   = (float*)(w + 1084160);        //    2816 B
  float* P1p   = (float*)(w + 1086976);        // 8650752 B  [64][16][11][192]
  float* S_p   = (float*)(w + 9737728);        //   45056 B  [64][16][11]
  float* m1_p  = (float*)(w + 9782784);        //   45056 B
  float* WihT  = (float*)(w + 9827840);        //  442368 B  [192][576]
  float* WhhT  = (float*)(w + 10270208);       //  442368 B  [192][576]
  float* WkT   = (float*)(w + 10712576);       //  147456 B  [192][192]

  k_tr<<<63, 256, 0, stream>>>(Wih, Whh, Wk, WihT, WhhT, WkT);
  k_prep<<<dim3(NB, 4), 192, 0, stream>>>(ln_slots_w, ln_slots_b, Wq, bq, WkT, bk,
                                          ln_in_w, ln_in_b, noise, slots_mu, slots_sigma,
                                          slots, qt, t0g, cpg);
  for (int it = 0; it < 3; ++it) {
    k_iter<<<dim3(NB, NCHP), 256, 0, stream>>>(inputs, qt, t0g, cpg, attn_out, P1p, S_p, m1_p);
    k_step<<<dim3(NB, 4), 192, 0, stream>>>(P1p, m1_p, S_p, ln_in_w, ln_in_b, Wv, bv, slots,
                                            WihT, WhhT, bih, bhh, ln_mlp_w, ln_mlp_b,
                                            W1, b1, W2, b2, ln_slots_w, ln_slots_b,
                                            Wq, bq, WkT, bk, slots, slots_out, qt, t0g, cpg);
  }
}

// Round 3
// 759.987 us; speedup vs baseline: 1.1854x; 1.0155x over previous
//
#include <hip/hip_runtime.h>
#include <hip/hip_bf16.h>
#include <cstdint>
#include <cstddef>

#define DIM 192
#define NSL 11
#define NB 64
#define NN 4096
#define HIDN 128
#define NCHP 16        // chunks per batch in k_iter (256 rows each)
#define TROWS 32       // rows per LDS tile in k_iter (8 tiles per chunk)
#define NT 8
#define LN_EPS 1e-5f
#define EPS_A 1e-8f
#define SCALE_Q 0.07216878364870323f  // 192^-0.5

// ---------------------------------------------------------------- utilities
__device__ __forceinline__ float wred(float v) {
#pragma unroll
  for (int m = 32; m; m >>= 1) v += __shfl_xor(v, m, 64);
  return v;
}

// async global->LDS, 16B per lane. LDS dest is wave-uniform base + lane*16 (HW).
typedef const __attribute__((address_space(1))) void gas_void;
typedef __attribute__((address_space(3))) void las_void;
__device__ __forceinline__ void gload_lds16(const void* g, void* l) {
  __builtin_amdgcn_global_load_lds((gas_void*)g, (las_void*)l, 16, 0, 0);
}

// ---------------------------------------------------------------- one-time weight transpose (64x64 LDS tiles)
__global__ __launch_bounds__(256) void k_tr(
    const float* __restrict__ Wih, const float* __restrict__ Whh, const float* __restrict__ Wk,
    float* __restrict__ WihT, float* __restrict__ WhhT, float* __restrict__ WkT) {
  __shared__ float t[64][65];
  int tile = blockIdx.x;
  const float* src; float* dst; int R, C;
  if (tile < 27)      { src = Wih; dst = WihT; R = 576; C = 192; }
  else if (tile < 54) { src = Whh; dst = WhhT; R = 576; C = 192; tile -= 27; }
  else                { src = Wk;  dst = WkT;  R = 192; C = 192; tile -= 54; }
  const int ntc = C >> 6;
  const int tr = tile / ntc, tc = tile % ntc;
  const int lane = threadIdx.x & 63, w = threadIdx.x >> 6;
#pragma unroll
  for (int i = 0; i < 16; ++i) {
    int row = w * 16 + i;
    t[row][lane] = src[(size_t)(tr * 64 + row) * C + tc * 64 + lane];
  }
  __syncthreads();
#pragma unroll
  for (int i = 0; i < 16; ++i) {
    int row = w * 16 + i;
    dst[(size_t)(tc * 64 + row) * R + tr * 64 + lane] = t[lane][row];
  }
}

// ---------------------------------------------------------------- k_prep: grid (64,4), 3 slots/block
__global__ __launch_bounds__(192) void k_prep(
    const float* __restrict__ lnw, const float* __restrict__ lnb,
    const float* __restrict__ Wq, const float* __restrict__ bq,
    const float* __restrict__ WkT, const float* __restrict__ bk,
    const float* __restrict__ xw, const float* __restrict__ xb,
    const float* __restrict__ noise, const float* __restrict__ mu0, const float* __restrict__ sig,
    float* __restrict__ slots_ws,
    float* __restrict__ qt, float* __restrict__ t0g, float* __restrict__ cpg) {
  const int b = blockIdx.x, kg = blockIdx.y, tid = threadIdx.x;
  const int k0 = kg * 3, kcnt = (kg == 3) ? 2 : 3;
  const int wave = tid >> 6, lane = tid & 63;
  const int j = tid;
  __shared__ __align__(16) float sn[3][DIM];
  __shared__ __align__(16) float qb[3][DIM];
  __shared__ float red[3][3][2];

#pragma unroll
  for (int kk = 0; kk < 3; ++kk) {
    if (kk < kcnt) {
      float v = mu0[j] + sig[j] * noise[(size_t)(b * NSL + k0 + kk) * DIM + j];
      sn[kk][j] = v;
      slots_ws[(size_t)(b * NSL + k0 + kk) * DIM + j] = v;
    } else sn[kk][j] = 0.f;
  }
  __syncthreads();

  for (int kk = wave; kk < 3; kk += 3) {
    float a = sn[kk][lane], c = sn[kk][lane + 64], e = sn[kk][lane + 128];
    float s = wred(a + c + e), ss = wred(a * a + c * c + e * e);
    float mu = s * (1.0f / DIM), var = ss * (1.0f / DIM) - mu * mu;
    float rstd = rsqrtf(var + LN_EPS);
    sn[kk][lane]       = (a - mu) * rstd * lnw[lane]       + lnb[lane];
    sn[kk][lane + 64]  = (c - mu) * rstd * lnw[lane + 64]  + lnb[lane + 64];
    sn[kk][lane + 128] = (e - mu) * rstd * lnw[lane + 128] + lnb[lane + 128];
  }
  __syncthreads();

  float acc[3];
  const float bj = bq[j];
#pragma unroll
  for (int kk = 0; kk < 3; ++kk) acc[kk] = bj;
  for (int d = 0; d < DIM; d += 4) {
    float w0 = Wq[(d + 0) * DIM + j], w1 = Wq[(d + 1) * DIM + j];
    float w2 = Wq[(d + 2) * DIM + j], w3 = Wq[(d + 3) * DIM + j];
#pragma unroll
    for (int kk = 0; kk < 3; ++kk) {
      float4 s4 = *(const float4*)&sn[kk][d];
      acc[kk] = fmaf(s4.w, w3, fmaf(s4.z, w2, fmaf(s4.y, w1, fmaf(s4.x, w0, acc[kk]))));
    }
  }
#pragma unroll
  for (int kk = 0; kk < 3; ++kk) qb[kk][j] = acc[kk];
  __syncthreads();

  float qk[3];
#pragma unroll
  for (int kk = 0; kk < 3; ++kk) qk[kk] = 0.f;
  for (int d = 0; d < DIM; d += 4) {
    float w0 = WkT[(d + 0) * DIM + j], w1 = WkT[(d + 1) * DIM + j];
    float w2 = WkT[(d + 2) * DIM + j], w3 = WkT[(d + 3) * DIM + j];
#pragma unroll
    for (int kk = 0; kk < 3; ++kk) {
      float4 q4 = *(const float4*)&qb[kk][d];
      qk[kk] = fmaf(q4.w, w3, fmaf(q4.z, w2, fmaf(q4.y, w1, fmaf(q4.x, w0, qk[kk]))));
    }
  }
  const float wj = xw[j], bxj = xb[j], bkj = bk[j];
#pragma unroll
  for (int kk = 0; kk < 3; ++kk) {
    float qtv = SCALE_Q * wj * qk[kk];
    if (kk < kcnt) qt[(size_t)(b * NSL + k0 + kk) * DIM + j] = qtv;
    float r1 = wred(qtv);
    float r2 = wred(SCALE_Q * (bxj * qk[kk] + qb[kk][j] * bkj));
    if (lane == 0) { red[wave][kk][0] = r1; red[wave][kk][1] = r2; }
  }
  __syncthreads();
  if (tid < kcnt) {
    t0g[b * NSL + k0 + tid] = red[0][tid][0] + red[1][tid][0] + red[2][tid][0];
    cpg[b * NSL + k0 + tid] = red[0][tid][1] + red[1][tid][1] + red[2][tid][1];
  }
}

// ---------------------------------------------------------------- fused iteration kernel
// R10 (resubmit after infra failure): single 32-row tile (LDS ~35 KB) -> 4
// blocks/CU; cross-block TLP replaces the double-buffer. Acc merge is 2-phase
// pairwise (128x33 fits one tile buf).
__global__ __launch_bounds__(256, 4) void k_iter(
    const float* __restrict__ x, const float* __restrict__ qt,
    const float* __restrict__ t0g, const float* __restrict__ cpg,
    float* __restrict__ attn_out, float* __restrict__ P1p,
    float* __restrict__ S_p, float* __restrict__ m1_p) {
  __shared__ __align__(16) float xs[TROWS * DIM];      // 24576 B
  __shared__ __align__(16) float qs[NSL * DIM];        // 8448 B
  __shared__ __align__(16) float a_lds[TROWS][12];     // 1536 B
  __shared__ float rs_lds[TROWS];
  __shared__ float t0s[NSL], cps[NSL];
  __shared__ float redS[4][NSL], redM[4][NSL];

  const int b = blockIdx.x, ch = blockIdx.y, tid = threadIdx.x;
  const int lane = tid & 63, wv = tid >> 6;
  const int widx = tid & 15, g = tid >> 4;

  const float* xbase = x + ((size_t)b * NN + ch * 256) * DIM;

  // issue tile-0 DMA first so it overlaps the q/t0/cp staging below
#pragma unroll
  for (int i = 0; i < 6; ++i) {
    int c = i * 4 + wv;                                 // 24 x 1024B chunks
    gload_lds16(xbase + c * 256 + lane * 4, &xs[c * 256]);
  }
  {
    const float4* src = (const float4*)(qt + (size_t)b * NSL * DIM);   // 528 float4
    float4* dst = (float4*)qs;
    dst[tid] = src[tid];
    dst[256 + tid] = src[256 + tid];
    if (tid < 16) dst[512 + tid] = src[512 + tid];
  }
  if (tid < NSL) { t0s[tid] = t0g[b * NSL + tid]; cps[tid] = cpg[b * NSL + tid]; }

  float acc[3][NSL], sS[NSL], sM[NSL];
#pragma unroll
  for (int k = 0; k < NSL; ++k) {
    acc[0][k] = 0.f; acc[1][k] = 0.f; acc[2][k] = 0.f;
    sS[k] = 0.f; sM[k] = 0.f;
  }

#pragma unroll 1
  for (int T = 0; T < NT; ++T) {
    if (T == 0) {
      __syncthreads();                                  // drains DMA + qs writes
    } else {
      __syncthreads();                                  // all waves done reading xs
      const float* src = xbase + (size_t)T * TROWS * DIM;
#pragma unroll
      for (int i = 0; i < 6; ++i) {
        int c = i * 4 + wv;
        gload_lds16(src + c * 256 + lane * 4, &xs[c * 256]);
      }
      asm volatile("s_waitcnt vmcnt(0)" ::: "memory");
      __builtin_amdgcn_s_barrier();                     // tile staged, visible
    }

    // ---- dots + LN stats: 16-lane group g owns rows {2g, 2g+1}
    float dot[2][NSL], st_s[2], st_ss[2];
#pragma unroll
    for (int rr = 0; rr < 2; ++rr) {
      st_s[rr] = 0.f; st_ss[rr] = 0.f;
#pragma unroll
      for (int k = 0; k < NSL; ++k) dot[rr][k] = 0.f;
    }
#pragma unroll
    for (int w = 0; w < 3; ++w) {
      const int c4 = widx + 16 * w;
      float4 xr[2];
#pragma unroll
      for (int rr = 0; rr < 2; ++rr) {
        xr[rr] = ((const float4*)xs)[(2 * g + rr) * 48 + c4];
        st_s[rr] += (xr[rr].x + xr[rr].y) + (xr[rr].z + xr[rr].w);
        st_ss[rr] = fmaf(xr[rr].x, xr[rr].x, fmaf(xr[rr].y, xr[rr].y,
                    fmaf(xr[rr].z, xr[rr].z, fmaf(xr[rr].w, xr[rr].w, st_ss[rr]))));
      }
#pragma unroll
      for (int k = 0; k < NSL; ++k) {
        float4 qv = *(const float4*)&qs[k * DIM + 4 * c4];
#pragma unroll
        for (int rr = 0; rr < 2; ++rr)
          dot[rr][k] = fmaf(xr[rr].w, qv.w, fmaf(xr[rr].z, qv.z,
                       fmaf(xr[rr].y, qv.y, fmaf(xr[rr].x, qv.x, dot[rr][k]))));
      }
    }
#pragma unroll
    for (int m = 1; m <= 8; m <<= 1) {
#pragma unroll
      for (int rr = 0; rr < 2; ++rr) {
        st_s[rr] += __shfl_xor(st_s[rr], m, 64);
        st_ss[rr] += __shfl_xor(st_ss[rr], m, 64);
#pragma unroll
        for (int k = 0; k < NSL; ++k) dot[rr][k] += __shfl_xor(dot[rr][k], m, 64);
      }
    }
    // ---- softmax: widx==0 handles row 2g, widx==8 handles row 2g+1.
    if ((widx & 7) == 0) {
      const int hi = widx >> 3;
      const int r = 2 * g + hi;
      float dsel[NSL];
#pragma unroll
      for (int k = 0; k < NSL; ++k) dsel[k] = (widx == 0) ? dot[0][k] : dot[1][k];
      float sts  = (widx == 0) ? st_s[0]  : st_s[1];
      float stss = (widx == 0) ? st_ss[0] : st_ss[1];
      float mu = sts * (1.0f / DIM);
      float var = stss * (1.0f / DIM) - mu * mu;
      float rstd = rsqrtf(var + LN_EPS);
      float murstd = mu * rstd;
      float dv[NSL];
#pragma unroll
      for (int k = 0; k < NSL; ++k) dv[k] = fmaf(rstd, dsel[k], fmaf(-murstd, t0s[k], cps[k]));
      float mx = dv[0];
#pragma unroll
      for (int k = 1; k < NSL; ++k) mx = fmaxf(mx, dv[k]);
      float es[NSL], sum = 0.f;
#pragma unroll
      for (int k = 0; k < NSL; ++k) { es[k] = __expf(dv[k] - mx); sum += es[k]; }
      float inv = 1.0f / sum;
#pragma unroll
      for (int k = 0; k < NSL; ++k) {
        float a = fmaf(es[k], inv, EPS_A);
        a_lds[r][k] = a;
        sS[k] += a;
        sM[k] = fmaf(a, murstd, sM[k]);
      }
      rs_lds[r] = rstd;
    }
    asm volatile("s_waitcnt lgkmcnt(0)" ::: "memory");  // a_lds/rs_lds committed
    __builtin_amdgcn_s_barrier();

    // ---- attn_out: 352 values, 32-float coalesced runs
    {
      int idx = tid;
      attn_out[((size_t)(b * NSL + (idx >> 5))) * NN + ch * 256 + T * TROWS + (idx & 31)]
          = a_lds[idx & 31][idx >> 5];
      idx = tid + 256;
      if (idx < NSL * TROWS)
        attn_out[((size_t)(b * NSL + (idx >> 5))) * NN + ch * 256 + T * TROWS + (idx & 31)]
            = a_lds[idx & 31][idx >> 5];
    }
    // ---- PV accumulate: wave wv owns rows 4i+wv
#pragma unroll 4
    for (int i = 0; i < 8; ++i) {
      const int r = 4 * i + wv;
      float rst = rs_lds[r];
      float4 a0 = *(const float4*)&a_lds[r][0];
      float4 a1 = *(const float4*)&a_lds[r][4];
      float4 a2 = *(const float4*)&a_lds[r][8];
#pragma unroll
      for (int j = 0; j < 3; ++j) {
        const int col = lane + 64 * j;
        float t1 = rst * xs[r * DIM + col];
        acc[j][0]  = fmaf(a0.x, t1, acc[j][0]);
        acc[j][1]  = fmaf(a0.y, t1, acc[j][1]);
        acc[j][2]  = fmaf(a0.z, t1, acc[j][2]);
        acc[j][3]  = fmaf(a0.w, t1, acc[j][3]);
        acc[j][4]  = fmaf(a1.x, t1, acc[j][4]);
        acc[j][5]  = fmaf(a1.y, t1, acc[j][5]);
        acc[j][6]  = fmaf(a1.z, t1, acc[j][6]);
        acc[j][7]  = fmaf(a1.w, t1, acc[j][7]);
        acc[j][8]  = fmaf(a2.x, t1, acc[j][8]);
        acc[j][9]  = fmaf(a2.y, t1, acc[j][9]);
        acc[j][10] = fmaf(a2.z, t1, acc[j][10]);
      }
    }
  }

  // ---- 2-phase pairwise acc merge into xs (128x33 = 4224 floats <= 6144)
  __syncthreads();
  float* accbuf = &xs[0];
  const int slot = tid & 127;
  if (wv < 2) {
#pragma unroll
    for (int j = 0; j < 3; ++j)
#pragma unroll
      for (int k = 0; k < NSL; ++k)
        accbuf[slot * 33 + j * 11 + k] = acc[j][k];
  }
  __syncthreads();
  if (wv >= 2) {
#pragma unroll
    for (int j = 0; j < 3; ++j)
#pragma unroll
      for (int k = 0; k < NSL; ++k)
        accbuf[slot * 33 + j * 11 + k] += acc[j][k];
  }
  __syncthreads();
  if (tid < DIM) {
    const int l = tid & 63, j = tid >> 6;
#pragma unroll
    for (int k = 0; k < NSL; ++k) {
      float v = accbuf[l * 33 + j * 11 + k] + accbuf[(64 + l) * 33 + j * 11 + k];
      P1p[(((size_t)b * NCHP + ch) * NSL + k) * DIM + tid] = v;
    }
  }
#pragma unroll
  for (int k = 0; k < NSL; ++k) { sS[k] = wred(sS[k]); sM[k] = wred(sM[k]); }
  if (lane == 0) {
#pragma unroll
    for (int k = 0; k < NSL; ++k) { redS[wv][k] = sS[k]; redM[wv][k] = sM[k]; }
  }
  __syncthreads();
  if (tid < NSL) {
    S_p[((size_t)b * NCHP + ch) * NSL + tid]  = redS[0][tid] + redS[1][tid] + redS[2][tid] + redS[3][tid];
    m1_p[((size_t)b * NCHP + ch) * NSL + tid] = redM[0][tid] + redM[1][tid] + redM[2][tid] + redM[3][tid];
  }
}

// ---------------------------------------------------------------- k_step: grid (64,11), 1 slot/block
// R10: was grid (64,4) = 256 blocks x 3 waves = 3 waves/CU -> pure latency
// (~105us for ~0.3 GFLOP). One slot per block -> 704 blocks, 2.75 blocks/CU,
// ~8 waves/CU; LN phases done redundantly per wave (no idle waves).
__global__ __launch_bounds__(192) void k_step(
    const float* __restrict__ P1p, const float* __restrict__ m1_p, const float* __restrict__ S_p,
    const float* __restrict__ xw, const float* __restrict__ xb,
    const float* __restrict__ Wv, const float* __restrict__ bv,
    const float* __restrict__ slots_in,
    const float* __restrict__ WihT, const float* __restrict__ WhhT,
    const float* __restrict__ bih, const float* __restrict__ bhh,
    const float* __restrict__ mw, const float* __restrict__ mb,
    const float* __restrict__ W1, const float* __restrict__ b1,
    const float* __restrict__ W2, const float* __restrict__ b2,
    const float* __restrict__ sw, const float* __restrict__ sb,
    const float* __restrict__ Wq, const float* __restrict__ bq,
    const float* __restrict__ WkT, const float* __restrict__ bk,
    float* __restrict__ slots_ws, float* __restrict__ slots_out,
    float* __restrict__ qt, float* __restrict__ t0g, float* __restrict__ cpg) {
  const int b = blockIdx.x, k = blockIdx.y, tid = threadIdx.x;
  const int wave = tid >> 6, lane = tid & 63;
  const int j = tid;
  __shared__ __align__(16) float u[DIM];
  __shared__ __align__(16) float hp[DIM];
  __shared__ __align__(16) float h[DIM];
  __shared__ __align__(16) float hid[HIDN];
  __shared__ float red[3][2];

  // ---- gather attention output for this (b,k)
  {
    float p = 0.f, S = 0.f, M = 0.f;
#pragma unroll
    for (int ch = 0; ch < NCHP; ++ch) {
      p += P1p[(((size_t)b * NCHP + ch) * NSL + k) * DIM + j];
      S += S_p[((size_t)b * NCHP + ch) * NSL + k];
      M += m1_p[((size_t)b * NCHP + ch) * NSL + k];
    }
    float inv = 1.0f / S;
    u[j]  = xw[j] * (p - M) * inv + xb[j];
    hp[j] = slots_in[(size_t)(b * NSL + k) * DIM + j];
  }
  __syncthreads();

  // ---- updates = u @ Wv + bv
  float upd = bv[j];
#pragma unroll 2
  for (int d = 0; d < DIM; d += 4) {
    float4 u4 = *(const float4*)&u[d];
    upd = fmaf(u4.x, Wv[(d + 0) * DIM + j],
          fmaf(u4.y, Wv[(d + 1) * DIM + j],
          fmaf(u4.z, Wv[(d + 2) * DIM + j],
          fmaf(u4.w, Wv[(d + 3) * DIM + j], upd))));
  }
  __syncthreads();
  u[j] = upd;
  __syncthreads();

  // ---- GRU cell
  float xr = bih[j], xz = bih[DIM + j], xn = bih[2 * DIM + j];
  float hr = bhh[j], hz = bhh[DIM + j], hn = bhh[2 * DIM + j];
#pragma unroll 2
  for (int d = 0; d < DIM; d += 4) {
    float4 u4 = *(const float4*)&u[d];
    float4 p4 = *(const float4*)&hp[d];
    float us[4] = {u4.x, u4.y, u4.z, u4.w};
    float ps[4] = {p4.x, p4.y, p4.z, p4.w};
#pragma unroll
    for (int dd = 0; dd < 4; ++dd) {
      const float* ihrow = WihT + (size_t)(d + dd) * 576;
      const float* hhrow = WhhT + (size_t)(d + dd) * 576;
      xr = fmaf(us[dd], ihrow[j], xr);
      xz = fmaf(us[dd], ihrow[192 + j], xz);
      xn = fmaf(us[dd], ihrow[384 + j], xn);
      hr = fmaf(ps[dd], hhrow[j], hr);
      hz = fmaf(ps[dd], hhrow[192 + j], hz);
      hn = fmaf(ps[dd], hhrow[384 + j], hn);
    }
  }
  float hv;
  {
    float r = 1.f / (1.f + __expf(-(xr + hr)));
    float z = 1.f / (1.f + __expf(-(xz + hz)));
    float n = tanhf(xn + r * hn);
    hv = (1.f - z) * n + z * hp[j];
    h[j] = hv;
  }
  __syncthreads();

  // ---- LN_mlp (each wave computes full row redundantly; same-value writes)
  {
    float a = h[lane], c = h[lane + 64], e = h[lane + 128];
    float s = wred(a + c + e), ss = wred(a * a + c * c + e * e);
    float mu = s * (1.0f / DIM), var = ss * (1.0f / DIM) - mu * mu;
    float rstd = rsqrtf(var + LN_EPS);
    u[lane]       = (a - mu) * rstd * mw[lane]       + mb[lane];
    u[lane + 64]  = (c - mu) * rstd * mw[lane + 64]  + mb[lane + 64];
    u[lane + 128] = (e - mu) * rstd * mw[lane + 128] + mb[lane + 128];
  }
  __syncthreads();

  // ---- MLP W1 + relu (128 outputs)
  if (tid < HIDN) {
    float acc = b1[tid];
#pragma unroll 2
    for (int d = 0; d < DIM; d += 4) {
      float4 m4 = *(const float4*)&u[d];
      acc = fmaf(m4.x, W1[(d + 0) * HIDN + tid],
            fmaf(m4.y, W1[(d + 1) * HIDN + tid],
            fmaf(m4.z, W1[(d + 2) * HIDN + tid],
            fmaf(m4.w, W1[(d + 3) * HIDN + tid], acc))));
    }
    hid[tid] = fmaxf(acc, 0.f);
  }
  __syncthreads();

  // ---- MLP W2 + residual
  float outv;
  {
    float acc = b2[j];
#pragma unroll 2
    for (int c = 0; c < HIDN; c += 4) {
      float4 h4 = *(const float4*)&hid[c];
      acc = fmaf(h4.x, W2[(c + 0) * DIM + j],
            fmaf(h4.y, W2[(c + 1) * DIM + j],
            fmaf(h4.z, W2[(c + 2) * DIM + j],
            fmaf(h4.w, W2[(c + 3) * DIM + j], acc))));
    }
    outv = hv + acc;
    size_t gi = (size_t)(b * NSL + k) * DIM + j;
    slots_ws[gi] = outv;
    slots_out[gi] = outv;
    hp[j] = outv;
  }
  __syncthreads();

  // ---- LN_slots (redundant per wave)
  {
    float a = hp[lane], c = hp[lane + 64], e = hp[lane + 128];
    float s = wred(a + c + e), ss = wred(a * a + c * c + e * e);
    float mu = s * (1.0f / DIM), var = ss * (1.0f / DIM) - mu * mu;
    float rstd = rsqrtf(var + LN_EPS);
    u[lane]       = (a - mu) * rstd * sw[lane]       + sb[lane];
    u[lane + 64]  = (c - mu) * rstd * sw[lane + 64]  + sb[lane + 64];
    u[lane + 128] = (e - mu) * rstd * sw[lane + 128] + sb[lane + 128];
  }
  __syncthreads();

  // ---- q = LN(slots) @ Wq + bq
  float qacc = bq[j];
#pragma unroll 2
  for (int d = 0; d < DIM; d += 4) {
    float4 s4 = *(const float4*)&u[d];
    qacc = fmaf(s4.x, Wq[(d + 0) * DIM + j],
           fmaf(s4.y, Wq[(d + 1) * DIM + j],
           fmaf(s4.z, Wq[(d + 2) * DIM + j],
           fmaf(s4.w, Wq[(d + 3) * DIM + j], qacc))));
  }
  __syncthreads();
  h[j] = qacc;
  __syncthreads();

  // ---- qt = (q @ Wk^T) row for the key-projection fusion
  float qk = 0.f;
#pragma unroll 2
  for (int d = 0; d < DIM; d += 4) {
    float4 q4 = *(const float4*)&h[d];
    qk = fmaf(q4.x, WkT[(d + 0) * DIM + j],
         fmaf(q4.y, WkT[(d + 1) * DIM + j],
         fmaf(q4.z, WkT[(d + 2) * DIM + j],
         fmaf(q4.w, WkT[(d + 3) * DIM + j], qk))));
  }
  {
    float qtv = SCALE_Q * xw[j] * qk;
    qt[(size_t)(b * NSL + k) * DIM + j] = qtv;
    float r1 = wred(qtv);
    float r2 = wred(SCALE_Q * (xb[j] * qk + qacc * bk[j]));
    if (lane == 0) { red[wave][0] = r1; red[wave][1] = r2; }
  }
  __syncthreads();
  if (tid == 0) {
    t0g[b * NSL + k] = red[0][0] + red[1][0] + red[2][0];
    cpg[b * NSL + k] = red[0][1] + red[1][1] + red[2][1];
  }
}

// ---------------------------------------------------------------- launch
extern "C" void kernel_launch(void* const* d_in, const int* in_sizes, int n_in,
                              void* d_out, int out_size, void* d_ws, size_t ws_size,
                              hipStream_t stream) {
  const float* inputs      = (const float*)d_in[0];
  const float* noise       = (const float*)d_in[1];
  const float* slots_mu    = (const float*)d_in[2];
  const float* slots_sigma = (const float*)d_in[3];
  const float* ln_in_w     = (const float*)d_in[4];
  const float* ln_in_b     = (const float*)d_in[5];
  const float* ln_slots_w  = (const float*)d_in[6];
  const float* ln_slots_b  = (const float*)d_in[7];
  const float* ln_mlp_w    = (const float*)d_in[8];
  const float* ln_mlp_b    = (const float*)d_in[9];
  const float* Wq  = (const float*)d_in[10];
  const float* bq  = (const float*)d_in[11];
  const float* Wk  = (const float*)d_in[12];
  const float* bk  = (const float*)d_in[13];
  const float* Wv  = (const float*)d_in[14];
  const float* bv  = (const float*)d_in[15];
  const float* Wih = (const float*)d_in[16];
  const float* Whh = (const float*)d_in[17];
  const float* bih = (const float*)d_in[18];
  const float* bhh = (const float*)d_in[19];
  const float* W1  = (const float*)d_in[20];
  const float* b1  = (const float*)d_in[21];
  const float* W2  = (const float*)d_in[22];
  const float* b2  = (const float*)d_in[23];

  float* out = (float*)d_out;
  float* slots_out = out;                      // [64,11,192] fp32
  float* attn_out  = out + NB * NSL * DIM;     // [64,11,4096] fp32

  char* w = (char*)d_ws;
  float* slots = (float*)w;                    //  540672 B
  float* qt    = (float*)(w + 540672);         //  540672 B
  float* t0g   = (float*)(w + 1081344);        //    2816 B
  float* cpg   = (float*)(w + 1084160);        //    2816 B
  float* P1p   = (float*)(w + 1086976);        // 8650752 B  [64][16][11][192]
  float* S_p   = (float*)(w + 9737728);        //   45056 B  [64][16][11]
  float* m1_p  = (float*)(w + 9782784);        //   45056 B
  float* WihT  = (float*)(w + 9827840);        //  442368 B  [192][576]
  float* WhhT  = (float*)(w + 10270208);       //  442368 B  [192][576]
  float* WkT   = (float*)(w + 10712576);       //  147456 B  [192][192]

  k_tr<<<63, 256, 0, stream>>>(Wih, Whh, Wk, WihT, WhhT, WkT);
  k_prep<<<dim3(NB, 4), 192, 0, stream>>>(ln_slots_w, ln_slots_b, Wq, bq, WkT, bk,
                                          ln_in_w, ln_in_b, noise, slots_mu, slots_sigma,
                                          slots, qt, t0g, cpg);
  for (int it = 0; it < 3; ++it) {
    k_iter<<<dim3(NB, NCHP), 256, 0, stream>>>(inputs, qt, t0g, cpg, attn_out, P1p, S_p, m1_p);
    k_step<<<dim3(NB, NSL), 192, 0, stream>>>(P1p, m1_p, S_p, ln_in_w, ln_in_b, Wv, bv, slots,
                                              WihT, WhhT, bih, bhh, ln_mlp_w, ln_mlp_b,
                                              W1, b1, W2, b2, ln_slots_w, ln_slots_b,
                                              Wq, bq, WkT, bk, slots, slots_out, qt, t0g, cpg);
  }
}

// Round 4
// 695.033 us; speedup vs baseline: 1.2962x; 1.0935x over previous
//
#include <hip/hip_runtime.h>
#include <hip/hip_bf16.h>
#include <cstdint>
#include <cstddef>

#define DIM 192
#define NSL 11
#define NB 64
#define NN 4096
#define HIDN 128
#define NCHP 16        // chunks per batch in k_iter (256 rows each)
#define TROWS 32       // rows per LDS tile in k_iter (8 tiles per chunk)
#define NT 8
#define LN_EPS 1e-5f
#define EPS_A 1e-8f
#define SCALE_Q 0.07216878364870323f  // 192^-0.5

// ---------------------------------------------------------------- utilities
__device__ __forceinline__ float wred(float v) {
#pragma unroll
  for (int m = 32; m; m >>= 1) v += __shfl_xor(v, m, 64);
  return v;
}

// async global->LDS, 16B per lane. LDS dest is wave-uniform base + lane*16 (HW).
typedef const __attribute__((address_space(1))) void gas_void;
typedef __attribute__((address_space(3))) void las_void;
__device__ __forceinline__ void gload_lds16(const void* g, void* l) {
  __builtin_amdgcn_global_load_lds((gas_void*)g, (las_void*)l, 16, 0, 0);
}

// ---------------------------------------------------------------- one-time weight transpose (64x64 LDS tiles)
__global__ __launch_bounds__(256) void k_tr(
    const float* __restrict__ Wih, const float* __restrict__ Whh, const float* __restrict__ Wk,
    float* __restrict__ WihT, float* __restrict__ WhhT, float* __restrict__ WkT) {
  __shared__ float t[64][65];
  int tile = blockIdx.x;
  const float* src; float* dst; int R, C;
  if (tile < 27)      { src = Wih; dst = WihT; R = 576; C = 192; }
  else if (tile < 54) { src = Whh; dst = WhhT; R = 576; C = 192; tile -= 27; }
  else                { src = Wk;  dst = WkT;  R = 192; C = 192; tile -= 54; }
  const int ntc = C >> 6;
  const int tr = tile / ntc, tc = tile % ntc;
  const int lane = threadIdx.x & 63, w = threadIdx.x >> 6;
#pragma unroll
  for (int i = 0; i < 16; ++i) {
    int row = w * 16 + i;
    t[row][lane] = src[(size_t)(tr * 64 + row) * C + tc * 64 + lane];
  }
  __syncthreads();
#pragma unroll
  for (int i = 0; i < 16; ++i) {
    int row = w * 16 + i;
    dst[(size_t)(tc * 64 + row) * R + tr * 64 + lane] = t[lane][row];
  }
}

// ---------------------------------------------------------------- k_prep: grid (64,4), 3 slots/block
__global__ __launch_bounds__(192) void k_prep(
    const float* __restrict__ lnw, const float* __restrict__ lnb,
    const float* __restrict__ Wq, const float* __restrict__ bq,
    const float* __restrict__ WkT, const float* __restrict__ bk,
    const float* __restrict__ xw, const float* __restrict__ xb,
    const float* __restrict__ noise, const float* __restrict__ mu0, const float* __restrict__ sig,
    float* __restrict__ slots_ws,
    float* __restrict__ qt, float* __restrict__ t0g, float* __restrict__ cpg) {
  const int b = blockIdx.x, kg = blockIdx.y, tid = threadIdx.x;
  const int k0 = kg * 3, kcnt = (kg == 3) ? 2 : 3;
  const int wave = tid >> 6, lane = tid & 63;
  const int j = tid;
  __shared__ __align__(16) float sn[3][DIM];
  __shared__ __align__(16) float qb[3][DIM];
  __shared__ float red[3][3][2];

#pragma unroll
  for (int kk = 0; kk < 3; ++kk) {
    if (kk < kcnt) {
      float v = mu0[j] + sig[j] * noise[(size_t)(b * NSL + k0 + kk) * DIM + j];
      sn[kk][j] = v;
      slots_ws[(size_t)(b * NSL + k0 + kk) * DIM + j] = v;
    } else sn[kk][j] = 0.f;
  }
  __syncthreads();

  for (int kk = wave; kk < 3; kk += 3) {
    float a = sn[kk][lane], c = sn[kk][lane + 64], e = sn[kk][lane + 128];
    float s = wred(a + c + e), ss = wred(a * a + c * c + e * e);
    float mu = s * (1.0f / DIM), var = ss * (1.0f / DIM) - mu * mu;
    float rstd = rsqrtf(var + LN_EPS);
    sn[kk][lane]       = (a - mu) * rstd * lnw[lane]       + lnb[lane];
    sn[kk][lane + 64]  = (c - mu) * rstd * lnw[lane + 64]  + lnb[lane + 64];
    sn[kk][lane + 128] = (e - mu) * rstd * lnw[lane + 128] + lnb[lane + 128];
  }
  __syncthreads();

  float acc[3];
  const float bj = bq[j];
#pragma unroll
  for (int kk = 0; kk < 3; ++kk) acc[kk] = bj;
  for (int d = 0; d < DIM; d += 4) {
    float w0 = Wq[(d + 0) * DIM + j], w1 = Wq[(d + 1) * DIM + j];
    float w2 = Wq[(d + 2) * DIM + j], w3 = Wq[(d + 3) * DIM + j];
#pragma unroll
    for (int kk = 0; kk < 3; ++kk) {
      float4 s4 = *(const float4*)&sn[kk][d];
      acc[kk] = fmaf(s4.w, w3, fmaf(s4.z, w2, fmaf(s4.y, w1, fmaf(s4.x, w0, acc[kk]))));
    }
  }
#pragma unroll
  for (int kk = 0; kk < 3; ++kk) qb[kk][j] = acc[kk];
  __syncthreads();

  float qk[3];
#pragma unroll
  for (int kk = 0; kk < 3; ++kk) qk[kk] = 0.f;
  for (int d = 0; d < DIM; d += 4) {
    float w0 = WkT[(d + 0) * DIM + j], w1 = WkT[(d + 1) * DIM + j];
    float w2 = WkT[(d + 2) * DIM + j], w3 = WkT[(d + 3) * DIM + j];
#pragma unroll
    for (int kk = 0; kk < 3; ++kk) {
      float4 q4 = *(const float4*)&qb[kk][d];
      qk[kk] = fmaf(q4.w, w3, fmaf(q4.z, w2, fmaf(q4.y, w1, fmaf(q4.x, w0, qk[kk]))));
    }
  }
  const float wj = xw[j], bxj = xb[j], bkj = bk[j];
#pragma unroll
  for (int kk = 0; kk < 3; ++kk) {
    float qtv = SCALE_Q * wj * qk[kk];
    if (kk < kcnt) qt[(size_t)(b * NSL + k0 + kk) * DIM + j] = qtv;
    float r1 = wred(qtv);
    float r2 = wred(SCALE_Q * (bxj * qk[kk] + qb[kk][j] * bkj));
    if (lane == 0) { red[wave][kk][0] = r1; red[wave][kk][1] = r2; }
  }
  __syncthreads();
  if (tid < kcnt) {
    t0g[b * NSL + k0 + tid] = red[0][tid][0] + red[1][tid][0] + red[2][tid][0];
    cpg[b * NSL + k0 + tid] = red[0][tid][1] + red[1][tid][1] + red[2][tid][1];
  }
}

// ---------------------------------------------------------------- fused iteration kernel
// R11: R10's launch_bounds(256,4) made the allocator target 64 VGPR -> acc[3][11]
// spilled (WRITE 52.7 MB vs 20 MB true). waves_per_eu(4,4) pins exactly 4
// waves/EU (VGPR cap 128); demand ~105 fits -> no spill, 4 blocks/CU kept.
__global__ __launch_bounds__(256) __attribute__((amdgpu_waves_per_eu(4, 4))) void k_iter(
    const float* __restrict__ x, const float* __restrict__ qt,
    const float* __restrict__ t0g, const float* __restrict__ cpg,
    float* __restrict__ attn_out, float* __restrict__ P1p,
    float* __restrict__ S_p, float* __restrict__ m1_p) {
  __shared__ __align__(16) float xs[TROWS * DIM];      // 24576 B
  __shared__ __align__(16) float qs[NSL * DIM];        // 8448 B
  __shared__ __align__(16) float a_lds[TROWS][12];     // 1536 B
  __shared__ float rs_lds[TROWS];
  __shared__ float t0s[NSL], cps[NSL];
  __shared__ float redS[4][NSL], redM[4][NSL];

  const int b = blockIdx.x, ch = blockIdx.y, tid = threadIdx.x;
  const int lane = tid & 63, wv = tid >> 6;
  const int widx = tid & 15, g = tid >> 4;

  const float* xbase = x + ((size_t)b * NN + ch * 256) * DIM;

  // issue tile-0 DMA first so it overlaps the q/t0/cp staging below
#pragma unroll
  for (int i = 0; i < 6; ++i) {
    int c = i * 4 + wv;                                 // 24 x 1024B chunks
    gload_lds16(xbase + c * 256 + lane * 4, &xs[c * 256]);
  }
  {
    const float4* src = (const float4*)(qt + (size_t)b * NSL * DIM);   // 528 float4
    float4* dst = (float4*)qs;
    dst[tid] = src[tid];
    dst[256 + tid] = src[256 + tid];
    if (tid < 16) dst[512 + tid] = src[512 + tid];
  }
  if (tid < NSL) { t0s[tid] = t0g[b * NSL + tid]; cps[tid] = cpg[b * NSL + tid]; }

  float acc[3][NSL], sS[NSL], sM[NSL];
#pragma unroll
  for (int k = 0; k < NSL; ++k) {
    acc[0][k] = 0.f; acc[1][k] = 0.f; acc[2][k] = 0.f;
    sS[k] = 0.f; sM[k] = 0.f;
  }

#pragma unroll 1
  for (int T = 0; T < NT; ++T) {
    if (T == 0) {
      __syncthreads();                                  // drains DMA + qs writes
    } else {
      __syncthreads();                                  // all waves done reading xs
      const float* src = xbase + (size_t)T * TROWS * DIM;
#pragma unroll
      for (int i = 0; i < 6; ++i) {
        int c = i * 4 + wv;
        gload_lds16(src + c * 256 + lane * 4, &xs[c * 256]);
      }
      asm volatile("s_waitcnt vmcnt(0)" ::: "memory");
      __builtin_amdgcn_s_barrier();                     // tile staged, visible
    }

    // ---- dots + LN stats: 16-lane group g owns rows {2g, 2g+1}
    float dot[2][NSL], st_s[2], st_ss[2];
#pragma unroll
    for (int rr = 0; rr < 2; ++rr) {
      st_s[rr] = 0.f; st_ss[rr] = 0.f;
#pragma unroll
      for (int k = 0; k < NSL; ++k) dot[rr][k] = 0.f;
    }
#pragma unroll
    for (int w = 0; w < 3; ++w) {
      const int c4 = widx + 16 * w;
      float4 xr[2];
#pragma unroll
      for (int rr = 0; rr < 2; ++rr) {
        xr[rr] = ((const float4*)xs)[(2 * g + rr) * 48 + c4];
        st_s[rr] += (xr[rr].x + xr[rr].y) + (xr[rr].z + xr[rr].w);
        st_ss[rr] = fmaf(xr[rr].x, xr[rr].x, fmaf(xr[rr].y, xr[rr].y,
                    fmaf(xr[rr].z, xr[rr].z, fmaf(xr[rr].w, xr[rr].w, st_ss[rr]))));
      }
#pragma unroll
      for (int k = 0; k < NSL; ++k) {
        float4 qv = *(const float4*)&qs[k * DIM + 4 * c4];
#pragma unroll
        for (int rr = 0; rr < 2; ++rr)
          dot[rr][k] = fmaf(xr[rr].w, qv.w, fmaf(xr[rr].z, qv.z,
                       fmaf(xr[rr].y, qv.y, fmaf(xr[rr].x, qv.x, dot[rr][k]))));
      }
    }
#pragma unroll
    for (int m = 1; m <= 8; m <<= 1) {
#pragma unroll
      for (int rr = 0; rr < 2; ++rr) {
        st_s[rr] += __shfl_xor(st_s[rr], m, 64);
        st_ss[rr] += __shfl_xor(st_ss[rr], m, 64);
#pragma unroll
        for (int k = 0; k < NSL; ++k) dot[rr][k] += __shfl_xor(dot[rr][k], m, 64);
      }
    }
    // ---- softmax: widx==0 handles row 2g, widx==8 handles row 2g+1.
    if ((widx & 7) == 0) {
      const int hi = widx >> 3;
      const int r = 2 * g + hi;
      float dsel[NSL];
#pragma unroll
      for (int k = 0; k < NSL; ++k) dsel[k] = (widx == 0) ? dot[0][k] : dot[1][k];
      float sts  = (widx == 0) ? st_s[0]  : st_s[1];
      float stss = (widx == 0) ? st_ss[0] : st_ss[1];
      float mu = sts * (1.0f / DIM);
      float var = stss * (1.0f / DIM) - mu * mu;
      float rstd = rsqrtf(var + LN_EPS);
      float murstd = mu * rstd;
      float dv[NSL];
#pragma unroll
      for (int k = 0; k < NSL; ++k) dv[k] = fmaf(rstd, dsel[k], fmaf(-murstd, t0s[k], cps[k]));
      float mx = dv[0];
#pragma unroll
      for (int k = 1; k < NSL; ++k) mx = fmaxf(mx, dv[k]);
      float es[NSL], sum = 0.f;
#pragma unroll
      for (int k = 0; k < NSL; ++k) { es[k] = __expf(dv[k] - mx); sum += es[k]; }
      float inv = 1.0f / sum;
#pragma unroll
      for (int k = 0; k < NSL; ++k) {
        float a = fmaf(es[k], inv, EPS_A);
        a_lds[r][k] = a;
        sS[k] += a;
        sM[k] = fmaf(a, murstd, sM[k]);
      }
      rs_lds[r] = rstd;
    }
    asm volatile("s_waitcnt lgkmcnt(0)" ::: "memory");  // a_lds/rs_lds committed
    __builtin_amdgcn_s_barrier();

    // ---- attn_out: 352 values, 32-float coalesced runs
    {
      int idx = tid;
      attn_out[((size_t)(b * NSL + (idx >> 5))) * NN + ch * 256 + T * TROWS + (idx & 31)]
          = a_lds[idx & 31][idx >> 5];
      idx = tid + 256;
      if (idx < NSL * TROWS)
        attn_out[((size_t)(b * NSL + (idx >> 5))) * NN + ch * 256 + T * TROWS + (idx & 31)]
            = a_lds[idx & 31][idx >> 5];
    }
    // ---- PV accumulate: wave wv owns rows 4i+wv
#pragma unroll 4
    for (int i = 0; i < 8; ++i) {
      const int r = 4 * i + wv;
      float rst = rs_lds[r];
      float4 a0 = *(const float4*)&a_lds[r][0];
      float4 a1 = *(const float4*)&a_lds[r][4];
      float4 a2 = *(const float4*)&a_lds[r][8];
#pragma unroll
      for (int j = 0; j < 3; ++j) {
        const int col = lane + 64 * j;
        float t1 = rst * xs[r * DIM + col];
        acc[j][0]  = fmaf(a0.x, t1, acc[j][0]);
        acc[j][1]  = fmaf(a0.y, t1, acc[j][1]);
        acc[j][2]  = fmaf(a0.z, t1, acc[j][2]);
        acc[j][3]  = fmaf(a0.w, t1, acc[j][3]);
        acc[j][4]  = fmaf(a1.x, t1, acc[j][4]);
        acc[j][5]  = fmaf(a1.y, t1, acc[j][5]);
        acc[j][6]  = fmaf(a1.z, t1, acc[j][6]);
        acc[j][7]  = fmaf(a1.w, t1, acc[j][7]);
        acc[j][8]  = fmaf(a2.x, t1, acc[j][8]);
        acc[j][9]  = fmaf(a2.y, t1, acc[j][9]);
        acc[j][10] = fmaf(a2.z, t1, acc[j][10]);
      }
    }
  }

  // ---- 2-phase pairwise acc merge into xs (128x33 = 4224 floats <= 6144)
  __syncthreads();
  float* accbuf = &xs[0];
  const int slot = tid & 127;
  if (wv < 2) {
#pragma unroll
    for (int j = 0; j < 3; ++j)
#pragma unroll
      for (int k = 0; k < NSL; ++k)
        accbuf[slot * 33 + j * 11 + k] = acc[j][k];
  }
  __syncthreads();
  if (wv >= 2) {
#pragma unroll
    for (int j = 0; j < 3; ++j)
#pragma unroll
      for (int k = 0; k < NSL; ++k)
        accbuf[slot * 33 + j * 11 + k] += acc[j][k];
  }
  __syncthreads();
  if (tid < DIM) {
    const int l = tid & 63, j = tid >> 6;
#pragma unroll
    for (int k = 0; k < NSL; ++k) {
      float v = accbuf[l * 33 + j * 11 + k] + accbuf[(64 + l) * 33 + j * 11 + k];
      P1p[(((size_t)b * NCHP + ch) * NSL + k) * DIM + tid] = v;
    }
  }
#pragma unroll
  for (int k = 0; k < NSL; ++k) { sS[k] = wred(sS[k]); sM[k] = wred(sM[k]); }
  if (lane == 0) {
#pragma unroll
    for (int k = 0; k < NSL; ++k) { redS[wv][k] = sS[k]; redM[wv][k] = sM[k]; }
  }
  __syncthreads();
  if (tid < NSL) {
    S_p[((size_t)b * NCHP + ch) * NSL + tid]  = redS[0][tid] + redS[1][tid] + redS[2][tid] + redS[3][tid];
    m1_p[((size_t)b * NCHP + ch) * NSL + tid] = redM[0][tid] + redM[1][tid] + redM[2][tid] + redM[3][tid];
  }
}

// ---------------------------------------------------------------- k_step: grid (64,4), 768 threads, 3 slots/block
// R11: R10's (64,11)x192 tripled weight traffic (1.07 GB) at 3 waves/block;
// R9's (64,4)x192 amortized weights but was 3 waves/CU latency-bound. This
// version: 3 slots/block (weights read once per block, 384 MB total) AND 12
// waves/block via 4-way K-split: thread (q,j) accumulates d in [48q,48q+48),
// partials reduced through LDS. 1 block/CU, ~520 loads/thread.
#define TPBS 768
__global__ __launch_bounds__(TPBS) void k_step(
    const float* __restrict__ P1p, const float* __restrict__ m1_p, const float* __restrict__ S_p,
    const float* __restrict__ xw, const float* __restrict__ xb,
    const float* __restrict__ Wv, const float* __restrict__ bv,
    const float* __restrict__ slots_in,
    const float* __restrict__ WihT, const float* __restrict__ WhhT,
    const float* __restrict__ bih, const float* __restrict__ bhh,
    const float* __restrict__ mw, const float* __restrict__ mb,
    const float* __restrict__ W1, const float* __restrict__ b1,
    const float* __restrict__ W2, const float* __restrict__ b2,
    const float* __restrict__ sw, const float* __restrict__ sb,
    const float* __restrict__ Wq, const float* __restrict__ bq,
    const float* __restrict__ WkT, const float* __restrict__ bk,
    float* __restrict__ slots_ws, float* __restrict__ slots_out,
    float* __restrict__ qt, float* __restrict__ t0g, float* __restrict__ cpg) {
  const int b = blockIdx.x, kg = blockIdx.y, tid = threadIdx.x;
  const int k0 = kg * 3, kcnt = (kg == 3) ? 2 : 3;
  const int q = tid / 192;            // d-quarter, wave-uniform (192 = 3 waves)
  const int j = tid - q * 192;        // output column
  const int lane = tid & 63;

  __shared__ __align__(16) float red[4 * 18 * 192];   // 55296 B partial buffer
  __shared__ __align__(16) float u[3][DIM];
  __shared__ __align__(16) float hp[3][DIM];
  __shared__ __align__(16) float h[3][DIM];
  __shared__ __align__(16) float hid[3][HIDN];
  __shared__ float sSp[3][16], sMp[3][16];
  __shared__ float redw[3][3][2];

#define RED(qq, gg, jj) red[(((qq) * 18 + (gg)) * 192) + (jj)]

  // slot indices, clamped so kg==3's phantom 3rd slot reads valid memory
  int kidx[3];
#pragma unroll
  for (int kk = 0; kk < 3; ++kk) { int t = k0 + kk; kidx[kk] = t > NSL - 1 ? NSL - 1 : t; }

  // ---------- A: attention gather -> u = LN-premul input, hp = slots_prev
#pragma unroll
  for (int kk = 0; kk < 3; ++kk) {
    float p = 0.f;
#pragma unroll
    for (int c = 0; c < 4; ++c) {
      int ch = q * 4 + c;
      p += P1p[(((size_t)b * NCHP + ch) * NSL + kidx[kk]) * DIM + j];
    }
    RED(q, kk, j) = p;
  }
  if (tid < 48) {
    int kk = tid >> 4, ch = tid & 15;
    sSp[kk][ch] = S_p[((size_t)b * NCHP + ch) * NSL + kidx[kk]];
    sMp[kk][ch] = m1_p[((size_t)b * NCHP + ch) * NSL + kidx[kk]];
  }
  if (q == 0) {
#pragma unroll
    for (int kk = 0; kk < 3; ++kk)
      hp[kk][j] = slots_in[(size_t)(b * NSL + kidx[kk]) * DIM + j];
  }
  __syncthreads();
  if (tid < 576) {                    // reducer mapping: kk = q, column = j
    const int kk = q;
    float p = RED(0, kk, j) + RED(1, kk, j) + RED(2, kk, j) + RED(3, kk, j);
    float S = 0.f, M = 0.f;
#pragma unroll
    for (int ch = 0; ch < 16; ++ch) { S += sSp[kk][ch]; M += sMp[kk][ch]; }
    u[kk][j] = xw[j] * (p - M) / S + xb[j];
  }
  __syncthreads();

  // ---------- B: updates = u @ Wv + bv
  {
    float p0 = 0.f, p1 = 0.f, p2 = 0.f;
    const int d0 = q * 48;
#pragma unroll 4
    for (int d = d0; d < d0 + 48; ++d) {
      float w = Wv[d * DIM + j];
      p0 = fmaf(u[0][d], w, p0);
      p1 = fmaf(u[1][d], w, p1);
      p2 = fmaf(u[2][d], w, p2);
    }
    RED(q, 0, j) = p0; RED(q, 1, j) = p1; RED(q, 2, j) = p2;
  }
  __syncthreads();
  if (tid < 576) {
    const int kk = q;
    u[kk][j] = bv[j] + RED(0, kk, j) + RED(1, kk, j) + RED(2, kk, j) + RED(3, kk, j);
  }
  __syncthreads();

  // ---------- C: GRU gates (6 GEMV columns x 3 slots)
  {
    float pxr[3] = {0,0,0}, pxz[3] = {0,0,0}, pxn[3] = {0,0,0};
    float phr[3] = {0,0,0}, phz[3] = {0,0,0}, phn[3] = {0,0,0};
    const int d0 = q * 48;
#pragma unroll 2
    for (int d = d0; d < d0 + 48; ++d) {
      const float* ihrow = WihT + (size_t)d * 576;
      const float* hhrow = WhhT + (size_t)d * 576;
      float ar = ihrow[j], az = ihrow[192 + j], an = ihrow[384 + j];
      float br = hhrow[j], bz = hhrow[192 + j], bn = hhrow[384 + j];
#pragma unroll
      for (int kk = 0; kk < 3; ++kk) {
        float uv = u[kk][d], pv = hp[kk][d];
        pxr[kk] = fmaf(uv, ar, pxr[kk]);
        pxz[kk] = fmaf(uv, az, pxz[kk]);
        pxn[kk] = fmaf(uv, an, pxn[kk]);
        phr[kk] = fmaf(pv, br, phr[kk]);
        phz[kk] = fmaf(pv, bz, phz[kk]);
        phn[kk] = fmaf(pv, bn, phn[kk]);
      }
    }
#pragma unroll
    for (int kk = 0; kk < 3; ++kk) {
      RED(q, 0 + kk, j)  = pxr[kk];  RED(q, 3 + kk, j)  = pxz[kk];
      RED(q, 6 + kk, j)  = pxn[kk];  RED(q, 9 + kk, j)  = phr[kk];
      RED(q, 12 + kk, j) = phz[kk];  RED(q, 15 + kk, j) = phn[kk];
    }
  }
  __syncthreads();
  if (tid < 576) {
    const int kk = q;
    float xr = bih[j]       + RED(0,0+kk,j)  + RED(1,0+kk,j)  + RED(2,0+kk,j)  + RED(3,0+kk,j);
    float xz = bih[192 + j] + RED(0,3+kk,j)  + RED(1,3+kk,j)  + RED(2,3+kk,j)  + RED(3,3+kk,j);
    float xn = bih[384 + j] + RED(0,6+kk,j)  + RED(1,6+kk,j)  + RED(2,6+kk,j)  + RED(3,6+kk,j);
    float hr = bhh[j]       + RED(0,9+kk,j)  + RED(1,9+kk,j)  + RED(2,9+kk,j)  + RED(3,9+kk,j);
    float hz = bhh[192 + j] + RED(0,12+kk,j) + RED(1,12+kk,j) + RED(2,12+kk,j) + RED(3,12+kk,j);
    float hn = bhh[384 + j] + RED(0,15+kk,j) + RED(1,15+kk,j) + RED(2,15+kk,j) + RED(3,15+kk,j);
    float r = 1.f / (1.f + __expf(-(xr + hr)));
    float z = 1.f / (1.f + __expf(-(xz + hz)));
    float n = tanhf(xn + r * hn);
    h[kk][j] = (1.f - z) * n + z * hp[kk][j];
  }
  __syncthreads();

  // ---------- D: LN_mlp(h) -> u   (waves 0-2, one slot each)
  {
    const int wv = tid >> 6;
    if (wv < 3) {
      const int kk = wv;
      float a = h[kk][lane], c = h[kk][lane + 64], e = h[kk][lane + 128];
      float s = wred(a + c + e), ss = wred(a * a + c * c + e * e);
      float mu = s * (1.0f / DIM), var = ss * (1.0f / DIM) - mu * mu;
      float rstd = rsqrtf(var + LN_EPS);
      u[kk][lane]       = (a - mu) * rstd * mw[lane]       + mb[lane];
      u[kk][lane + 64]  = (c - mu) * rstd * mw[lane + 64]  + mb[lane + 64];
      u[kk][lane + 128] = (e - mu) * rstd * mw[lane + 128] + mb[lane + 128];
    }
  }
  __syncthreads();

  // ---------- E: hid = relu(u @ W1 + b1)   (128 cols)
  if (j < HIDN) {
    float p0 = 0.f, p1 = 0.f, p2 = 0.f;
    const int d0 = q * 48;
#pragma unroll 4
    for (int d = d0; d < d0 + 48; ++d) {
      float w = W1[d * HIDN + j];
      p0 = fmaf(u[0][d], w, p0);
      p1 = fmaf(u[1][d], w, p1);
      p2 = fmaf(u[2][d], w, p2);
    }
    RED(q, 0, j) = p0; RED(q, 1, j) = p1; RED(q, 2, j) = p2;
  }
  __syncthreads();
  if (tid < 576 && j < HIDN) {
    const int kk = q;
    float v = b1[j] + RED(0, kk, j) + RED(1, kk, j) + RED(2, kk, j) + RED(3, kk, j);
    hid[kk][j] = fmaxf(v, 0.f);
  }
  __syncthreads();

  // ---------- F: slots = h + hid @ W2 + b2
  {
    float p0 = 0.f, p1 = 0.f, p2 = 0.f;
    const int c0 = q * 32;
#pragma unroll 4
    for (int c = c0; c < c0 + 32; ++c) {
      float w = W2[c * DIM + j];
      p0 = fmaf(hid[0][c], w, p0);
      p1 = fmaf(hid[1][c], w, p1);
      p2 = fmaf(hid[2][c], w, p2);
    }
    RED(q, 0, j) = p0; RED(q, 1, j) = p1; RED(q, 2, j) = p2;
  }
  __syncthreads();
  if (tid < 576) {
    const int kk = q;
    float outv = h[kk][j] + b2[j] + RED(0, kk, j) + RED(1, kk, j) + RED(2, kk, j) + RED(3, kk, j);
    if (kk < kcnt) {
      size_t gi = (size_t)(b * NSL + k0 + kk) * DIM + j;
      slots_ws[gi] = outv;
      slots_out[gi] = outv;
    }
    hp[kk][j] = outv;
  }
  __syncthreads();

  // ---------- G: LN_slots(hp) -> u   (waves 0-2)
  {
    const int wv = tid >> 6;
    if (wv < 3) {
      const int kk = wv;
      float a = hp[kk][lane], c = hp[kk][lane + 64], e = hp[kk][lane + 128];
      float s = wred(a + c + e), ss = wred(a * a + c * c + e * e);
      float mu = s * (1.0f / DIM), var = ss * (1.0f / DIM) - mu * mu;
      float rstd = rsqrtf(var + LN_EPS);
      u[kk][lane]       = (a - mu) * rstd * sw[lane]       + sb[lane];
      u[kk][lane + 64]  = (c - mu) * rstd * sw[lane + 64]  + sb[lane + 64];
      u[kk][lane + 128] = (e - mu) * rstd * sw[lane + 128] + sb[lane + 128];
    }
  }
  __syncthreads();

  // ---------- H: q = u @ Wq + bq -> h
  {
    float p0 = 0.f, p1 = 0.f, p2 = 0.f;
    const int d0 = q * 48;
#pragma unroll 4
    for (int d = d0; d < d0 + 48; ++d) {
      float w = Wq[d * DIM + j];
      p0 = fmaf(u[0][d], w, p0);
      p1 = fmaf(u[1][d], w, p1);
      p2 = fmaf(u[2][d], w, p2);
    }
    RED(q, 0, j) = p0; RED(q, 1, j) = p1; RED(q, 2, j) = p2;
  }
  __syncthreads();
  if (tid < 576) {
    const int kk = q;
    h[kk][j] = bq[j] + RED(0, kk, j) + RED(1, kk, j) + RED(2, kk, j) + RED(3, kk, j);
  }
  __syncthreads();

  // ---------- I: qk = h @ WkT -> u, then qt/t0g/cpg
  {
    float p0 = 0.f, p1 = 0.f, p2 = 0.f;
    const int d0 = q * 48;
#pragma unroll 4
    for (int d = d0; d < d0 + 48; ++d) {
      float w = WkT[d * DIM + j];
      p0 = fmaf(h[0][d], w, p0);
      p1 = fmaf(h[1][d], w, p1);
      p2 = fmaf(h[2][d], w, p2);
    }
    RED(q, 0, j) = p0; RED(q, 1, j) = p1; RED(q, 2, j) = p2;
  }
  __syncthreads();
  if (tid < 576) {
    const int kk = q;
    u[kk][j] = RED(0, kk, j) + RED(1, kk, j) + RED(2, kk, j) + RED(3, kk, j);
  }
  __syncthreads();
  if (tid < 192) {                    // waves 0-2 do the scalar reductions
    const int wv = tid >> 6;
    const float wxj = xw[j], bxj = xb[j], bkj = bk[j];
#pragma unroll
    for (int kk = 0; kk < 3; ++kk) {
      float qk = u[kk][j];
      float qv = h[kk][j];
      float qtv = SCALE_Q * wxj * qk;
      if (kk < kcnt) qt[(size_t)(b * NSL + k0 + kk) * DIM + j] = qtv;
      float r1 = wred(qtv);
      float r2 = wred(SCALE_Q * (bxj * qk + qv * bkj));
      if (lane == 0) { redw[wv][kk][0] = r1; redw[wv][kk][1] = r2; }
    }
  }
  __syncthreads();
  if (tid < kcnt) {
    t0g[b * NSL + k0 + tid] = redw[0][tid][0] + redw[1][tid][0] + redw[2][tid][0];
    cpg[b * NSL + k0 + tid] = redw[0][tid][1] + redw[1][tid][1] + redw[2][tid][1];
  }
#undef RED
}

// ---------------------------------------------------------------- launch
extern "C" void kernel_launch(void* const* d_in, const int* in_sizes, int n_in,
                              void* d_out, int out_size, void* d_ws, size_t ws_size,
                              hipStream_t stream) {
  const float* inputs      = (const float*)d_in[0];
  const float* noise       = (const float*)d_in[1];
  const float* slots_mu    = (const float*)d_in[2];
  const float* slots_sigma = (const float*)d_in[3];
  const float* ln_in_w     = (const float*)d_in[4];
  const float* ln_in_b     = (const float*)d_in[5];
  const float* ln_slots_w  = (const float*)d_in[6];
  const float* ln_slots_b  = (const float*)d_in[7];
  const float* ln_mlp_w    = (const float*)d_in[8];
  const float* ln_mlp_b    = (const float*)d_in[9];
  const float* Wq  = (const float*)d_in[10];
  const float* bq  = (const float*)d_in[11];
  const float* Wk  = (const float*)d_in[12];
  const float* bk  = (const float*)d_in[13];
  const float* Wv  = (const float*)d_in[14];
  const float* bv  = (const float*)d_in[15];
  const float* Wih = (const float*)d_in[16];
  const float* Whh = (const float*)d_in[17];
  const float* bih = (const float*)d_in[18];
  const float* bhh = (const float*)d_in[19];
  const float* W1  = (const float*)d_in[20];
  const float* b1  = (const float*)d_in[21];
  const float* W2  = (const float*)d_in[22];
  const float* b2  = (const float*)d_in[23];

  float* out = (float*)d_out;
  float* slots_out = out;                      // [64,11,192] fp32
  float* attn_out  = out + NB * NSL * DIM;     // [64,11,4096] fp32

  char* w = (char*)d_ws;
  float* slots = (float*)w;                    //  540672 B
  float* qt    = (float*)(w + 540672);         //  540672 B
  float* t0g   = (float*)(w + 1081344);        //    2816 B
  float* cpg   = (float*)(w + 1084160);        //    2816 B
  float* P1p   = (float*)(w + 1086976);        // 8650752 B  [64][16][11][192]
  float* S_p   = (float*)(w + 9737728);        //   45056 B  [64][16][11]
  float* m1_p  = (float*)(w + 9782784);        //   45056 B
  float* WihT  = (float*)(w + 9827840);        //  442368 B  [192][576]
  float* WhhT  = (float*)(w + 10270208);       //  442368 B  [192][576]
  float* WkT   = (float*)(w + 10712576);       //  147456 B  [192][192]

  k_tr<<<63, 256, 0, stream>>>(Wih, Whh, Wk, WihT, WhhT, WkT);
  k_prep<<<dim3(NB, 4), 192, 0, stream>>>(ln_slots_w, ln_slots_b, Wq, bq, WkT, bk,
                                          ln_in_w, ln_in_b, noise, slots_mu, slots_sigma,
                                          slots, qt, t0g, cpg);
  for (int it = 0; it < 3; ++it) {
    k_iter<<<dim3(NB, NCHP), 256, 0, stream>>>(inputs, qt, t0g, cpg, attn_out, P1p, S_p, m1_p);
    k_step<<<dim3(NB, 4), TPBS, 0, stream>>>(P1p, m1_p, S_p, ln_in_w, ln_in_b, Wv, bv, slots,
                                             WihT, WhhT, bih, bhh, ln_mlp_w, ln_mlp_b,
                                             W1, b1, W2, b2, ln_slots_w, ln_slots_b,
                                             Wq, bq, WkT, bk, slots, slots_out, qt, t0g, cpg);
  }
}

// Round 6
// 694.337 us; speedup vs baseline: 1.2975x; 1.0010x over previous
//
#include <hip/hip_runtime.h>
#include <hip/hip_bf16.h>
#include <cstdint>
#include <cstddef>

#define DIM 192
#define NSL 11
#define NB 64
#define NN 4096
#define HIDN 128
#define NCHP 16        // chunks per batch in k_iter (256 rows each)
#define TROWS 32       // rows per LDS tile in k_iter (8 tiles per chunk)
#define NT 8
#define LN_EPS 1e-5f
#define EPS_A 1e-8f
#define SCALE_Q 0.07216878364870323f  // 192^-0.5

// ---------------------------------------------------------------- utilities
__device__ __forceinline__ float wred(float v) {
#pragma unroll
  for (int m = 32; m; m >>= 1) v += __shfl_xor(v, m, 64);
  return v;
}

// async global->LDS, 16B per lane. LDS dest is wave-uniform base + lane*16 (HW).
typedef const __attribute__((address_space(1))) void gas_void;
typedef __attribute__((address_space(3))) void las_void;
__device__ __forceinline__ void gload_lds16(const void* g, void* l) {
  __builtin_amdgcn_global_load_lds((gas_void*)g, (las_void*)l, 16, 0, 0);
}

// ---------------------------------------------------------------- one-time weight transpose (64x64 LDS tiles)
__global__ __launch_bounds__(256) void k_tr(
    const float* __restrict__ Wih, const float* __restrict__ Whh, const float* __restrict__ Wk,
    float* __restrict__ WihT, float* __restrict__ WhhT, float* __restrict__ WkT) {
  __shared__ float t[64][65];
  int tile = blockIdx.x;
  const float* src; float* dst; int R, C;
  if (tile < 27)      { src = Wih; dst = WihT; R = 576; C = 192; }
  else if (tile < 54) { src = Whh; dst = WhhT; R = 576; C = 192; tile -= 27; }
  else                { src = Wk;  dst = WkT;  R = 192; C = 192; tile -= 54; }
  const int ntc = C >> 6;
  const int tr = tile / ntc, tc = tile % ntc;
  const int lane = threadIdx.x & 63, w = threadIdx.x >> 6;
#pragma unroll
  for (int i = 0; i < 16; ++i) {
    int row = w * 16 + i;
    t[row][lane] = src[(size_t)(tr * 64 + row) * C + tc * 64 + lane];
  }
  __syncthreads();
#pragma unroll
  for (int i = 0; i < 16; ++i) {
    int row = w * 16 + i;
    dst[(size_t)(tc * 64 + row) * R + tr * 64 + lane] = t[lane][row];
  }
}

// ---------------------------------------------------------------- k_prep: grid (64,4), 3 slots/block
__global__ __launch_bounds__(192) void k_prep(
    const float* __restrict__ lnw, const float* __restrict__ lnb,
    const float* __restrict__ Wq, const float* __restrict__ bq,
    const float* __restrict__ WkT, const float* __restrict__ bk,
    const float* __restrict__ xw, const float* __restrict__ xb,
    const float* __restrict__ noise, const float* __restrict__ mu0, const float* __restrict__ sig,
    float* __restrict__ slots_ws,
    float* __restrict__ qt, float* __restrict__ t0g, float* __restrict__ cpg) {
  const int b = blockIdx.x, kg = blockIdx.y, tid = threadIdx.x;
  const int k0 = kg * 3, kcnt = (kg == 3) ? 2 : 3;
  const int wave = tid >> 6, lane = tid & 63;
  const int j = tid;
  __shared__ __align__(16) float sn[3][DIM];
  __shared__ __align__(16) float qb[3][DIM];
  __shared__ float red[3][3][2];

#pragma unroll
  for (int kk = 0; kk < 3; ++kk) {
    if (kk < kcnt) {
      float v = mu0[j] + sig[j] * noise[(size_t)(b * NSL + k0 + kk) * DIM + j];
      sn[kk][j] = v;
      slots_ws[(size_t)(b * NSL + k0 + kk) * DIM + j] = v;
    } else sn[kk][j] = 0.f;
  }
  __syncthreads();

  for (int kk = wave; kk < 3; kk += 3) {
    float a = sn[kk][lane], c = sn[kk][lane + 64], e = sn[kk][lane + 128];
    float s = wred(a + c + e), ss = wred(a * a + c * c + e * e);
    float mu = s * (1.0f / DIM), var = ss * (1.0f / DIM) - mu * mu;
    float rstd = rsqrtf(var + LN_EPS);
    sn[kk][lane]       = (a - mu) * rstd * lnw[lane]       + lnb[lane];
    sn[kk][lane + 64]  = (c - mu) * rstd * lnw[lane + 64]  + lnb[lane + 64];
    sn[kk][lane + 128] = (e - mu) * rstd * lnw[lane + 128] + lnb[lane + 128];
  }
  __syncthreads();

  float acc[3];
  const float bj = bq[j];
#pragma unroll
  for (int kk = 0; kk < 3; ++kk) acc[kk] = bj;
  for (int d = 0; d < DIM; d += 4) {
    float w0 = Wq[(d + 0) * DIM + j], w1 = Wq[(d + 1) * DIM + j];
    float w2 = Wq[(d + 2) * DIM + j], w3 = Wq[(d + 3) * DIM + j];
#pragma unroll
    for (int kk = 0; kk < 3; ++kk) {
      float4 s4 = *(const float4*)&sn[kk][d];
      acc[kk] = fmaf(s4.w, w3, fmaf(s4.z, w2, fmaf(s4.y, w1, fmaf(s4.x, w0, acc[kk]))));
    }
  }
#pragma unroll
  for (int kk = 0; kk < 3; ++kk) qb[kk][j] = acc[kk];
  __syncthreads();

  float qk[3];
#pragma unroll
  for (int kk = 0; kk < 3; ++kk) qk[kk] = 0.f;
  for (int d = 0; d < DIM; d += 4) {
    float w0 = WkT[(d + 0) * DIM + j], w1 = WkT[(d + 1) * DIM + j];
    float w2 = WkT[(d + 2) * DIM + j], w3 = WkT[(d + 3) * DIM + j];
#pragma unroll
    for (int kk = 0; kk < 3; ++kk) {
      float4 q4 = *(const float4*)&qb[kk][d];
      qk[kk] = fmaf(q4.w, w3, fmaf(q4.z, w2, fmaf(q4.y, w1, fmaf(q4.x, w0, qk[kk]))));
    }
  }
  const float wj = xw[j], bxj = xb[j], bkj = bk[j];
#pragma unroll
  for (int kk = 0; kk < 3; ++kk) {
    float qtv = SCALE_Q * wj * qk[kk];
    if (kk < kcnt) qt[(size_t)(b * NSL + k0 + kk) * DIM + j] = qtv;
    float r1 = wred(qtv);
    float r2 = wred(SCALE_Q * (bxj * qk[kk] + qb[kk][j] * bkj));
    if (lane == 0) { red[wave][kk][0] = r1; red[wave][kk][1] = r2; }
  }
  __syncthreads();
  if (tid < kcnt) {
    t0g[b * NSL + k0 + tid] = red[0][tid][0] + red[1][tid][0] + red[2][tid][0];
    cpg[b * NSL + k0 + tid] = red[0][tid][1] + red[1][tid][1] + red[2][tid][1];
  }
}

// ---------------------------------------------------------------- fused iteration kernel
// R12 (resubmit after infra failure): three rounds prove the allocator targets
// 64 VGPR for this kernel no matter the occupancy hint (R3/R4: VGPR=64,
// acc[3][11] spilled, 33 MB excess WRITE). Fix is structural: PV ownership
// flips from (3 cols x 11 slots x 1/4 rows + LDS merge) to (1 col x 11 slots
// x ALL rows) per thread j<192 -> acc shrinks 33->11 regs, sS/sM move to 11
// threads of wave 3 (2 scalars), the 2-phase merge epilogue disappears.
// Peak live ~60 <= 64 -> no scratch.
__global__ __launch_bounds__(256) void k_iter(
    const float* __restrict__ x, const float* __restrict__ qt,
    const float* __restrict__ t0g, const float* __restrict__ cpg,
    float* __restrict__ attn_out, float* __restrict__ P1p,
    float* __restrict__ S_p, float* __restrict__ m1_p) {
  __shared__ __align__(16) float xs[TROWS * DIM];      // 24576 B
  __shared__ __align__(16) float qs[NSL * DIM];        // 8448 B
  __shared__ __align__(16) float a_lds[TROWS][12];     // 1536 B
  __shared__ float rs_lds[TROWS];                      // rstd per row
  __shared__ float mr_lds[TROWS];                      // mu*rstd per row
  __shared__ float t0s[NSL], cps[NSL];

  const int b = blockIdx.x, ch = blockIdx.y, tid = threadIdx.x;
  const int wv = tid >> 6;
  const int widx = tid & 15, g = tid >> 4;

  const float* xbase = x + ((size_t)b * NN + ch * 256) * DIM;

  // issue tile-0 DMA first so it overlaps the q/t0/cp staging below
#pragma unroll
  for (int i = 0; i < 6; ++i) {
    int c = i * 4 + wv;                                 // 24 x 1024B chunks
    gload_lds16(xbase + c * 256 + (tid & 63) * 4, &xs[c * 256]);
  }
  {
    const float4* src = (const float4*)(qt + (size_t)b * NSL * DIM);   // 528 float4
    float4* dst = (float4*)qs;
    dst[tid] = src[tid];
    dst[256 + tid] = src[256 + tid];
    if (tid < 16) dst[512 + tid] = src[512 + tid];
  }
  if (tid < NSL) { t0s[tid] = t0g[b * NSL + tid]; cps[tid] = cpg[b * NSL + tid]; }

  float acc[NSL];                 // thread j<192: full chunk-sum for column j
  float sSa = 0.f, sMa = 0.f;     // threads 192..202: slot sums
#pragma unroll
  for (int k = 0; k < NSL; ++k) acc[k] = 0.f;

#pragma unroll 1
  for (int T = 0; T < NT; ++T) {
    if (T == 0) {
      __syncthreads();                                  // drains DMA + qs writes
    } else {
      __syncthreads();                                  // all waves done with xs/a_lds
      const float* src = xbase + (size_t)T * TROWS * DIM;
#pragma unroll
      for (int i = 0; i < 6; ++i) {
        int c = i * 4 + wv;
        gload_lds16(src + c * 256 + (tid & 63) * 4, &xs[c * 256]);
      }
      asm volatile("s_waitcnt vmcnt(0)" ::: "memory");
      __builtin_amdgcn_s_barrier();                     // tile staged, visible
    }

    // ---- dots + LN stats: 16-lane group g owns rows {2g, 2g+1}
    float dot[2][NSL], st_s[2], st_ss[2];
#pragma unroll
    for (int rr = 0; rr < 2; ++rr) {
      st_s[rr] = 0.f; st_ss[rr] = 0.f;
#pragma unroll
      for (int k = 0; k < NSL; ++k) dot[rr][k] = 0.f;
    }
#pragma unroll
    for (int w = 0; w < 3; ++w) {
      const int c4 = widx + 16 * w;
      float4 xr[2];
#pragma unroll
      for (int rr = 0; rr < 2; ++rr) {
        xr[rr] = ((const float4*)xs)[(2 * g + rr) * 48 + c4];
        st_s[rr] += (xr[rr].x + xr[rr].y) + (xr[rr].z + xr[rr].w);
        st_ss[rr] = fmaf(xr[rr].x, xr[rr].x, fmaf(xr[rr].y, xr[rr].y,
                    fmaf(xr[rr].z, xr[rr].z, fmaf(xr[rr].w, xr[rr].w, st_ss[rr]))));
      }
#pragma unroll
      for (int k = 0; k < NSL; ++k) {
        float4 qv = *(const float4*)&qs[k * DIM + 4 * c4];
#pragma unroll
        for (int rr = 0; rr < 2; ++rr)
          dot[rr][k] = fmaf(xr[rr].w, qv.w, fmaf(xr[rr].z, qv.z,
                       fmaf(xr[rr].y, qv.y, fmaf(xr[rr].x, qv.x, dot[rr][k]))));
      }
    }
#pragma unroll
    for (int m = 1; m <= 8; m <<= 1) {
#pragma unroll
      for (int rr = 0; rr < 2; ++rr) {
        st_s[rr] += __shfl_xor(st_s[rr], m, 64);
        st_ss[rr] += __shfl_xor(st_ss[rr], m, 64);
#pragma unroll
        for (int k = 0; k < NSL; ++k) dot[rr][k] += __shfl_xor(dot[rr][k], m, 64);
      }
    }
    // ---- softmax: widx==0 handles row 2g, widx==8 handles row 2g+1.
    if ((widx & 7) == 0) {
      const int hi = widx >> 3;
      const int r = 2 * g + hi;
      float dsel[NSL];
#pragma unroll
      for (int k = 0; k < NSL; ++k) dsel[k] = (widx == 0) ? dot[0][k] : dot[1][k];
      float sts  = (widx == 0) ? st_s[0]  : st_s[1];
      float stss = (widx == 0) ? st_ss[0] : st_ss[1];
      float mu = sts * (1.0f / DIM);
      float var = stss * (1.0f / DIM) - mu * mu;
      float rstd = rsqrtf(var + LN_EPS);
      float murstd = mu * rstd;
      float dv[NSL];
#pragma unroll
      for (int k = 0; k < NSL; ++k) dv[k] = fmaf(rstd, dsel[k], fmaf(-murstd, t0s[k], cps[k]));
      float mx = dv[0];
#pragma unroll
      for (int k = 1; k < NSL; ++k) mx = fmaxf(mx, dv[k]);
      float es[NSL], sum = 0.f;
#pragma unroll
      for (int k = 0; k < NSL; ++k) { es[k] = __expf(dv[k] - mx); sum += es[k]; }
      float inv = 1.0f / sum;
#pragma unroll
      for (int k = 0; k < NSL; ++k) a_lds[r][k] = fmaf(es[k], inv, EPS_A);
      rs_lds[r] = rstd;
      mr_lds[r] = murstd;
    }
    asm volatile("s_waitcnt lgkmcnt(0)" ::: "memory");  // a_lds/rs/mr committed
    __builtin_amdgcn_s_barrier();

    if (tid < 192) {
      // ---- PV: thread owns column tid, iterates all 32 rows.
      // xs read: 64 consecutive lanes stride-1 (conflict-free); a_lds reads
      // are lane-uniform float4 broadcasts.
#pragma unroll 4
      for (int r = 0; r < TROWS; ++r) {
        float t1 = rs_lds[r] * xs[r * DIM + tid];
        float4 a0 = *(const float4*)&a_lds[r][0];
        float4 a1 = *(const float4*)&a_lds[r][4];
        float4 a2 = *(const float4*)&a_lds[r][8];
        acc[0]  = fmaf(a0.x, t1, acc[0]);
        acc[1]  = fmaf(a0.y, t1, acc[1]);
        acc[2]  = fmaf(a0.z, t1, acc[2]);
        acc[3]  = fmaf(a0.w, t1, acc[3]);
        acc[4]  = fmaf(a1.x, t1, acc[4]);
        acc[5]  = fmaf(a1.y, t1, acc[5]);
        acc[6]  = fmaf(a1.z, t1, acc[6]);
        acc[7]  = fmaf(a1.w, t1, acc[7]);
        acc[8]  = fmaf(a2.x, t1, acc[8]);
        acc[9]  = fmaf(a2.y, t1, acc[9]);
        acc[10] = fmaf(a2.z, t1, acc[10]);
      }
    } else {
      // ---- wave 3 upper: attn_out stores + slot-sum accumulation
      const int t = tid - 192;
#pragma unroll
      for (int i = 0; i < 6; ++i) {
        int idx = t + 64 * i;
        if (idx < NSL * TROWS)
          attn_out[((size_t)(b * NSL + (idx >> 5))) * NN + ch * 256 + T * TROWS + (idx & 31)]
              = a_lds[idx & 31][idx >> 5];
      }
      if (t < NSL) {
#pragma unroll 4
        for (int r = 0; r < TROWS; ++r) {
          float a = a_lds[r][t];
          sSa += a;
          sMa = fmaf(a, mr_lds[r], sMa);
        }
      }
    }
  }

  // ---- epilogue: direct writes (no cross-thread merge needed)
  if (tid < 192) {
#pragma unroll
    for (int k = 0; k < NSL; ++k)
      P1p[(((size_t)b * NCHP + ch) * NSL + k) * DIM + tid] = acc[k];
  } else if (tid - 192 < NSL) {
    const int t = tid - 192;
    S_p[((size_t)b * NCHP + ch) * NSL + t]  = sSa;
    m1_p[((size_t)b * NCHP + ch) * NSL + t] = sMa;
  }
}

// ---------------------------------------------------------------- k_step: grid (64,4), 768 threads, 3 slots/block
// (unchanged from R11 -- kept byte-identical so next round's rocprof top-5
// captures its counters once k_iter drops below it)
#define TPBS 768
__global__ __launch_bounds__(TPBS) void k_step(
    const float* __restrict__ P1p, const float* __restrict__ m1_p, const float* __restrict__ S_p,
    const float* __restrict__ xw, const float* __restrict__ xb,
    const float* __restrict__ Wv, const float* __restrict__ bv,
    const float* __restrict__ slots_in,
    const float* __restrict__ WihT, const float* __restrict__ WhhT,
    const float* __restrict__ bih, const float* __restrict__ bhh,
    const float* __restrict__ mw, const float* __restrict__ mb,
    const float* __restrict__ W1, const float* __restrict__ b1,
    const float* __restrict__ W2, const float* __restrict__ b2,
    const float* __restrict__ sw, const float* __restrict__ sb,
    const float* __restrict__ Wq, const float* __restrict__ bq,
    const float* __restrict__ WkT, const float* __restrict__ bk,
    float* __restrict__ slots_ws, float* __restrict__ slots_out,
    float* __restrict__ qt, float* __restrict__ t0g, float* __restrict__ cpg) {
  const int b = blockIdx.x, kg = blockIdx.y, tid = threadIdx.x;
  const int k0 = kg * 3, kcnt = (kg == 3) ? 2 : 3;
  const int q = tid / 192;            // d-quarter, wave-uniform (192 = 3 waves)
  const int j = tid - q * 192;        // output column
  const int lane = tid & 63;

  __shared__ __align__(16) float red[4 * 18 * 192];   // 55296 B partial buffer
  __shared__ __align__(16) float u[3][DIM];
  __shared__ __align__(16) float hp[3][DIM];
  __shared__ __align__(16) float h[3][DIM];
  __shared__ __align__(16) float hid[3][HIDN];
  __shared__ float sSp[3][16], sMp[3][16];
  __shared__ float redw[3][3][2];

#define RED(qq, gg, jj) red[(((qq) * 18 + (gg)) * 192) + (jj)]

  // slot indices, clamped so kg==3's phantom 3rd slot reads valid memory
  int kidx[3];
#pragma unroll
  for (int kk = 0; kk < 3; ++kk) { int t = k0 + kk; kidx[kk] = t > NSL - 1 ? NSL - 1 : t; }

  // ---------- A: attention gather -> u = LN-premul input, hp = slots_prev
#pragma unroll
  for (int kk = 0; kk < 3; ++kk) {
    float p = 0.f;
#pragma unroll
    for (int c = 0; c < 4; ++c) {
      int ch = q * 4 + c;
      p += P1p[(((size_t)b * NCHP + ch) * NSL + kidx[kk]) * DIM + j];
    }
    RED(q, kk, j) = p;
  }
  if (tid < 48) {
    int kk = tid >> 4, ch = tid & 15;
    sSp[kk][ch] = S_p[((size_t)b * NCHP + ch) * NSL + kidx[kk]];
    sMp[kk][ch] = m1_p[((size_t)b * NCHP + ch) * NSL + kidx[kk]];
  }
  if (q == 0) {
#pragma unroll
    for (int kk = 0; kk < 3; ++kk)
      hp[kk][j] = slots_in[(size_t)(b * NSL + kidx[kk]) * DIM + j];
  }
  __syncthreads();
  if (tid < 576) {                    // reducer mapping: kk = q, column = j
    const int kk = q;
    float p = RED(0, kk, j) + RED(1, kk, j) + RED(2, kk, j) + RED(3, kk, j);
    float S = 0.f, M = 0.f;
#pragma unroll
    for (int ch = 0; ch < 16; ++ch) { S += sSp[kk][ch]; M += sMp[kk][ch]; }
    u[kk][j] = xw[j] * (p - M) / S + xb[j];
  }
  __syncthreads();

  // ---------- B: updates = u @ Wv + bv
  {
    float p0 = 0.f, p1 = 0.f, p2 = 0.f;
    const int d0 = q * 48;
#pragma unroll 4
    for (int d = d0; d < d0 + 48; ++d) {
      float w = Wv[d * DIM + j];
      p0 = fmaf(u[0][d], w, p0);
      p1 = fmaf(u[1][d], w, p1);
      p2 = fmaf(u[2][d], w, p2);
    }
    RED(q, 0, j) = p0; RED(q, 1, j) = p1; RED(q, 2, j) = p2;
  }
  __syncthreads();
  if (tid < 576) {
    const int kk = q;
    u[kk][j] = bv[j] + RED(0, kk, j) + RED(1, kk, j) + RED(2, kk, j) + RED(3, kk, j);
  }
  __syncthreads();

  // ---------- C: GRU gates (6 GEMV columns x 3 slots)
  {
    float pxr[3] = {0,0,0}, pxz[3] = {0,0,0}, pxn[3] = {0,0,0};
    float phr[3] = {0,0,0}, phz[3] = {0,0,0}, phn[3] = {0,0,0};
    const int d0 = q * 48;
#pragma unroll 2
    for (int d = d0; d < d0 + 48; ++d) {
      const float* ihrow = WihT + (size_t)d * 576;
      const float* hhrow = WhhT + (size_t)d * 576;
      float ar = ihrow[j], az = ihrow[192 + j], an = ihrow[384 + j];
      float br = hhrow[j], bz = hhrow[192 + j], bn = hhrow[384 + j];
#pragma unroll
      for (int kk = 0; kk < 3; ++kk) {
        float uv = u[kk][d], pv = hp[kk][d];
        pxr[kk] = fmaf(uv, ar, pxr[kk]);
        pxz[kk] = fmaf(uv, az, pxz[kk]);
        pxn[kk] = fmaf(uv, an, pxn[kk]);
        phr[kk] = fmaf(pv, br, phr[kk]);
        phz[kk] = fmaf(pv, bz, phz[kk]);
        phn[kk] = fmaf(pv, bn, phn[kk]);
      }
    }
#pragma unroll
    for (int kk = 0; kk < 3; ++kk) {
      RED(q, 0 + kk, j)  = pxr[kk];  RED(q, 3 + kk, j)  = pxz[kk];
      RED(q, 6 + kk, j)  = pxn[kk];  RED(q, 9 + kk, j)  = phr[kk];
      RED(q, 12 + kk, j) = phz[kk];  RED(q, 15 + kk, j) = phn[kk];
    }
  }
  __syncthreads();
  if (tid < 576) {
    const int kk = q;
    float xr = bih[j]       + RED(0,0+kk,j)  + RED(1,0+kk,j)  + RED(2,0+kk,j)  + RED(3,0+kk,j);
    float xz = bih[192 + j] + RED(0,3+kk,j)  + RED(1,3+kk,j)  + RED(2,3+kk,j)  + RED(3,3+kk,j);
    float xn = bih[384 + j] + RED(0,6+kk,j)  + RED(1,6+kk,j)  + RED(2,6+kk,j)  + RED(3,6+kk,j);
    float hr = bhh[j]       + RED(0,9+kk,j)  + RED(1,9+kk,j)  + RED(2,9+kk,j)  + RED(3,9+kk,j);
    float hz = bhh[192 + j] + RED(0,12+kk,j) + RED(1,12+kk,j) + RED(2,12+kk,j) + RED(3,12+kk,j);
    float hn = bhh[384 + j] + RED(0,15+kk,j) + RED(1,15+kk,j) + RED(2,15+kk,j) + RED(3,15+kk,j);
    float r = 1.f / (1.f + __expf(-(xr + hr)));
    float z = 1.f / (1.f + __expf(-(xz + hz)));
    float n = tanhf(xn + r * hn);
    h[kk][j] = (1.f - z) * n + z * hp[kk][j];
  }
  __syncthreads();

  // ---------- D: LN_mlp(h) -> u   (waves 0-2, one slot each)
  {
    const int wv = tid >> 6;
    if (wv < 3) {
      const int kk = wv;
      float a = h[kk][lane], c = h[kk][lane + 64], e = h[kk][lane + 128];
      float s = wred(a + c + e), ss = wred(a * a + c * c + e * e);
      float mu = s * (1.0f / DIM), var = ss * (1.0f / DIM) - mu * mu;
      float rstd = rsqrtf(var + LN_EPS);
      u[kk][lane]       = (a - mu) * rstd * mw[lane]       + mb[lane];
      u[kk][lane + 64]  = (c - mu) * rstd * mw[lane + 64]  + mb[lane + 64];
      u[kk][lane + 128] = (e - mu) * rstd * mw[lane + 128] + mb[lane + 128];
    }
  }
  __syncthreads();

  // ---------- E: hid = relu(u @ W1 + b1)   (128 cols)
  if (j < HIDN) {
    float p0 = 0.f, p1 = 0.f, p2 = 0.f;
    const int d0 = q * 48;
#pragma unroll 4
    for (int d = d0; d < d0 + 48; ++d) {
      float w = W1[d * HIDN + j];
      p0 = fmaf(u[0][d], w, p0);
      p1 = fmaf(u[1][d], w, p1);
      p2 = fmaf(u[2][d], w, p2);
    }
    RED(q, 0, j) = p0; RED(q, 1, j) = p1; RED(q, 2, j) = p2;
  }
  __syncthreads();
  if (tid < 576 && j < HIDN) {
    const int kk = q;
    float v = b1[j] + RED(0, kk, j) + RED(1, kk, j) + RED(2, kk, j) + RED(3, kk, j);
    hid[kk][j] = fmaxf(v, 0.f);
  }
  __syncthreads();

  // ---------- F: slots = h + hid @ W2 + b2
  {
    float p0 = 0.f, p1 = 0.f, p2 = 0.f;
    const int c0 = q * 32;
#pragma unroll 4
    for (int c = c0; c < c0 + 32; ++c) {
      float w = W2[c * DIM + j];
      p0 = fmaf(hid[0][c], w, p0);
      p1 = fmaf(hid[1][c], w, p1);
      p2 = fmaf(hid[2][c], w, p2);
    }
    RED(q, 0, j) = p0; RED(q, 1, j) = p1; RED(q, 2, j) = p2;
  }
  __syncthreads();
  if (tid < 576) {
    const int kk = q;
    float outv = h[kk][j] + b2[j] + RED(0, kk, j) + RED(1, kk, j) + RED(2, kk, j) + RED(3, kk, j);
    if (kk < kcnt) {
      size_t gi = (size_t)(b * NSL + k0 + kk) * DIM + j;
      slots_ws[gi] = outv;
      slots_out[gi] = outv;
    }
    hp[kk][j] = outv;
  }
  __syncthreads();

  // ---------- G: LN_slots(hp) -> u   (waves 0-2)
  {
    const int wv = tid >> 6;
    if (wv < 3) {
      const int kk = wv;
      float a = hp[kk][lane], c = hp[kk][lane + 64], e = hp[kk][lane + 128];
      float s = wred(a + c + e), ss = wred(a * a + c * c + e * e);
      float mu = s * (1.0f / DIM), var = ss * (1.0f / DIM) - mu * mu;
      float rstd = rsqrtf(var + LN_EPS);
      u[kk][lane]       = (a - mu) * rstd * sw[lane]       + sb[lane];
      u[kk][lane + 64]  = (c - mu) * rstd * sw[lane + 64]  + sb[lane + 64];
      u[kk][lane + 128] = (e - mu) * rstd * sw[lane + 128] + sb[lane + 128];
    }
  }
  __syncthreads();

  // ---------- H: q = u @ Wq + bq -> h
  {
    float p0 = 0.f, p1 = 0.f, p2 = 0.f;
    const int d0 = q * 48;
#pragma unroll 4
    for (int d = d0; d < d0 + 48; ++d) {
      float w = Wq[d * DIM + j];
      p0 = fmaf(u[0][d], w, p0);
      p1 = fmaf(u[1][d], w, p1);
      p2 = fmaf(u[2][d], w, p2);
    }
    RED(q, 0, j) = p0; RED(q, 1, j) = p1; RED(q, 2, j) = p2;
  }
  __syncthreads();
  if (tid < 576) {
    const int kk = q;
    h[kk][j] = bq[j] + RED(0, kk, j) + RED(1, kk, j) + RED(2, kk, j) + RED(3, kk, j);
  }
  __syncthreads();

  // ---------- I: qk = h @ WkT -> u, then qt/t0g/cpg
  {
    float p0 = 0.f, p1 = 0.f, p2 = 0.f;
    const int d0 = q * 48;
#pragma unroll 4
    for (int d = d0; d < d0 + 48; ++d) {
      float w = WkT[d * DIM + j];
      p0 = fmaf(h[0][d], w, p0);
      p1 = fmaf(h[1][d], w, p1);
      p2 = fmaf(h[2][d], w, p2);
    }
    RED(q, 0, j) = p0; RED(q, 1, j) = p1; RED(q, 2, j) = p2;
  }
  __syncthreads();
  if (tid < 576) {
    const int kk = q;
    u[kk][j] = RED(0, kk, j) + RED(1, kk, j) + RED(2, kk, j) + RED(3, kk, j);
  }
  __syncthreads();
  if (tid < 192) {                    // waves 0-2 do the scalar reductions
    const int wv = tid >> 6;
    const float wxj = xw[j], bxj = xb[j], bkj = bk[j];
#pragma unroll
    for (int kk = 0; kk < 3; ++kk) {
      float qk = u[kk][j];
      float qv = h[kk][j];
      float qtv = SCALE_Q * wxj * qk;
      if (kk < kcnt) qt[(size_t)(b * NSL + k0 + kk) * DIM + j] = qtv;
      float r1 = wred(qtv);
      float r2 = wred(SCALE_Q * (bxj * qk + qv * bkj));
      if (lane == 0) { redw[wv][kk][0] = r1; redw[wv][kk][1] = r2; }
    }
  }
  __syncthreads();
  if (tid < kcnt) {
    t0g[b * NSL + k0 + tid] = redw[0][tid][0] + redw[1][tid][0] + redw[2][tid][0];
    cpg[b * NSL + k0 + tid] = redw[0][tid][1] + redw[1][tid][1] + redw[2][tid][1];
  }
#undef RED
}

// ---------------------------------------------------------------- launch
extern "C" void kernel_launch(void* const* d_in, const int* in_sizes, int n_in,
                              void* d_out, int out_size, void* d_ws, size_t ws_size,
                              hipStream_t stream) {
  const float* inputs      = (const float*)d_in[0];
  const float* noise       = (const float*)d_in[1];
  const float* slots_mu    = (const float*)d_in[2];
  const float* slots_sigma = (const float*)d_in[3];
  const float* ln_in_w     = (const float*)d_in[4];
  const float* ln_in_b     = (const float*)d_in[5];
  const float* ln_slots_w  = (const float*)d_in[6];
  const float* ln_slots_b  = (const float*)d_in[7];
  const float* ln_mlp_w    = (const float*)d_in[8];
  const float* ln_mlp_b    = (const float*)d_in[9];
  const float* Wq  = (const float*)d_in[10];
  const float* bq  = (const float*)d_in[11];
  const float* Wk  = (const float*)d_in[12];
  const float* bk  = (const float*)d_in[13];
  const float* Wv  = (const float*)d_in[14];
  const float* bv  = (const float*)d_in[15];
  const float* Wih = (const float*)d_in[16];
  const float* Whh = (const float*)d_in[17];
  const float* bih = (const float*)d_in[18];
  const float* bhh = (const float*)d_in[19];
  const float* W1  = (const float*)d_in[20];
  const float* b1  = (const float*)d_in[21];
  const float* W2  = (const float*)d_in[22];
  const float* b2  = (const float*)d_in[23];

  float* out = (float*)d_out;
  float* slots_out = out;                      // [64,11,192] fp32
  float* attn_out  = out + NB * NSL * DIM;     // [64,11,4096] fp32

  char* w = (char*)d_ws;
  float* slots = (float*)w;                    //  540672 B
  float* qt    = (float*)(w + 540672);         //  540672 B
  float* t0g   = (float*)(w + 1081344);        //    2816 B
  float* cpg   = (float*)(w + 1084160);        //    2816 B
  float* P1p   = (float*)(w + 1086976);        // 8650752 B  [64][16][11][192]
  float* S_p   = (float*)(w + 9737728);        //   45056 B  [64][16][11]
  float* m1_p  = (float*)(w + 9782784);        //   45056 B
  float* WihT  = (float*)(w + 9827840);        //  442368 B  [192][576]
  float* WhhT  = (float*)(w + 10270208);       //  442368 B  [192][576]
  float* WkT   = (float*)(w + 10712576);       //  147456 B  [192][192]

  k_tr<<<63, 256, 0, stream>>>(Wih, Whh, Wk, WihT, WhhT, WkT);
  k_prep<<<dim3(NB, 4), 192, 0, stream>>>(ln_slots_w, ln_slots_b, Wq, bq, WkT, bk,
                                          ln_in_w, ln_in_b, noise, slots_mu, slots_sigma,
                                          slots, qt, t0g, cpg);
  for (int it = 0; it < 3; ++it) {
    k_iter<<<dim3(NB, NCHP), 256, 0, stream>>>(inputs, qt, t0g, cpg, attn_out, P1p, S_p, m1_p);
    k_step<<<dim3(NB, 4), TPBS, 0, stream>>>(P1p, m1_p, S_p, ln_in_w, ln_in_b, Wv, bv, slots,
                                             WihT, WhhT, bih, bhh, ln_mlp_w, ln_mlp_b,
                                             W1, b1, W2, b2, ln_slots_w, ln_slots_b,
                                             Wq, bq, WkT, bk, slots, slots_out, qt, t0g, cpg);
  }
}